// Round 9
// baseline (220.927 us; speedup 1.0000x reference)
//
#include <hip/hip_runtime.h>
#include <hip/hip_bf16.h>
#include <math.h>

// Problem constants: BN=2, L=1024, DM=1024, D_STATE=16, D_CONV=4, EXPAND=2,
// D_INNER=2048. M = BN*L = 2048.
#define BN_   2
#define L_    1024
#define DM_   1024
#define DS_   16
#define DI_   2048
#define M_    (BN_ * L_)
#define NBC_  2176           // dt(2048) + Bm(16) + Cm(16) + pad(96), 17*128

typedef __attribute__((ext_vector_type(8))) short short8;
typedef __attribute__((ext_vector_type(4))) float f32x4;

__device__ __forceinline__ unsigned short f2b(float f) {
    union { float f; unsigned u; } x; x.f = f;
    unsigned r = x.u + 0x7fffu + ((x.u >> 16) & 1u);   // RNE
    return (unsigned short)(r >> 16);
}
__device__ __forceinline__ float b2f(unsigned short u) {
    union { unsigned u; float f; } x; x.u = ((unsigned)u) << 16; return x.f;
}

__device__ __forceinline__ void gload_lds16(const unsigned short* g, unsigned short* l) {
    __builtin_amdgcn_global_load_lds(
        (const __attribute__((address_space(1))) void*)g,
        (__attribute__((address_space(3))) void*)l, 16, 0, 0);
}

// counted vmcnt wait (T4): wait until at most N VMEM ops outstanding.
template<int N> __device__ __forceinline__ void waitcnt_vm() {
    if constexpr (N == 0)      asm volatile("s_waitcnt vmcnt(0)" ::: "memory");
    else if constexpr (N == 4) asm volatile("s_waitcnt vmcnt(4)" ::: "memory");
    else if constexpr (N == 6) asm volatile("s_waitcnt vmcnt(6)" ::: "memory");
    else static_assert(N == 0 || N == 4 || N == 6, "unsupported vmcnt");
}

// ---------------------------------------------------------------------------
// elementwise fp32 -> bf16 cast (n multiple of 4)
// ---------------------------------------------------------------------------
__global__ __launch_bounds__(256) void cast_bf16(
    const float* __restrict__ in, unsigned short* __restrict__ out, int n)
{
    const int i = (blockIdx.x * 256 + threadIdx.x) * 4;
    if (i >= n) return;
    float4 v = *(const float4*)(in + i);
    ushort4 o; o.x = f2b(v.x); o.y = f2b(v.y); o.z = f2b(v.z); o.w = f2b(v.w);
    *(ushort4*)(out + i) = o;
}

// ---------------------------------------------------------------------------
// transpose + cast: in fp32 [R][C] -> out bf16 [C][R].  R,C multiples of 32.
// ---------------------------------------------------------------------------
__global__ __launch_bounds__(256) void transpose_cast(
    const float* __restrict__ in, unsigned short* __restrict__ out, int R, int C)
{
    __shared__ float t[32][33];
    const int bx = blockIdx.x * 32;   // C dir
    const int by = blockIdx.y * 32;   // R dir
    const int tx = threadIdx.x & 31;
    const int ty = (threadIdx.x >> 5) * 4;
    #pragma unroll
    for (int j = 0; j < 4; ++j)
        t[ty + j][tx] = in[(size_t)(by + ty + j) * C + bx + tx];
    __syncthreads();
    #pragma unroll
    for (int j = 0; j < 4; ++j)
        out[(size_t)(bx + ty + j) * R + by + tx] = f2b(t[tx][ty + j]);
}

// ---------------------------------------------------------------------------
// pack B_w / C_w transposed into w2 rows 2048..2079 ([N][K] layout).
// ---------------------------------------------------------------------------
__global__ __launch_bounds__(256) void bc_pack(
    const float* __restrict__ Bw, const float* __restrict__ Cw,
    unsigned short* __restrict__ w2)
{
    const int idx = blockIdx.x * 256 + threadIdx.x;   // 32*2048
    const int r = idx >> 11;        // 0..31
    const int k = idx & 2047;
    const float* src = (r < 16) ? Bw : Cw;
    w2[(size_t)(2048 + r) * 2048 + k] = f2b(src[k * 16 + (r & 15)]);
}

// ---------------------------------------------------------------------------
// bf16 MFMA GEMM, 3-stage deep pipeline with counted vmcnt across raw
// s_barrier (T3+T4): tile k computes while k+1 is landing and k+2 is being
// issued; the per-step wait is vmcnt(LOADS) (k+2's loads stay in flight),
// NEVER vmcnt(0) in the main loop. Read-side XOR swizzle (conflict-free)
// and XCD-aware bijective block swizzle retained from R6-R8.
//   MODE 0: bf16 output, column-split at NS -> U0 | U1        (in_proj)
//   MODE 1: fp32; c<2048 softplus->F0; 2048..2063 ->F1(+b1);
//           2064..2079 ->F2(+b2); higher cols (pad) discarded  (dt+B+C)
//   MODE 2: fp32 single output F0                              (out_proj)
// ---------------------------------------------------------------------------
template<int BM, int BN, int MODE>
__global__ __launch_bounds__(256) void gemm_mfma(
    const unsigned short* __restrict__ A,   // [M][K] bf16
    const unsigned short* __restrict__ Bt,  // [N][K] bf16
    const float* __restrict__ b0, const float* __restrict__ b1,
    const float* __restrict__ b2,
    float* __restrict__ F0, float* __restrict__ F1, float* __restrict__ F2,
    unsigned short* __restrict__ U0, unsigned short* __restrict__ U1,
    int M, int N, int K, int NS)
{
    constexpr int MF    = BM / 32;            // m-frags per wave
    constexpr int NF    = BN / 32;            // n-frags per wave
    constexpr int ACW   = BM / 32;            // A 8-row chunks per wave per stage
    constexpr int BCW   = BN / 32;            // B 8-row chunks per wave per stage
    constexpr int LOADS = ACW + BCW;          // VMEM ops per wave per stage

    __shared__ unsigned short Asl[3][BM * 64];
    __shared__ unsigned short Bsl[3][BN * 64];

    const int tid  = threadIdx.x;
    const int wave = tid >> 6;
    const int lane = tid & 63;

    // XCD-aware bijective swizzle (all call sites have nwg % 8 == 0).
    const int gx  = gridDim.x, gy = gridDim.y;
    const int bid = blockIdx.y * gx + blockIdx.x;
    const int q   = (gx * gy) >> 3;
    const int nb  = (bid & 7) * q + (bid >> 3);
    const int by  = nb % gy;
    const int bx  = nb / gy;

    const int row0 = by * BM;
    const int col0 = bx * BN;
    const int wr   = (wave >> 1) * (BM / 2);
    const int wc   = (wave & 1) * (BN / 2);

    const int srow = lane >> 3;                          // row within 8-row chunk
    const int scol = ((lane & 7) ^ (lane >> 3)) * 8;     // pre-swizzled source col

    auto stage = [&](int buf, int kt) {
        #pragma unroll
        for (int i = 0; i < ACW; ++i) {
            const int ch = wave * ACW + i;
            gload_lds16(A + (size_t)(row0 + ch * 8 + srow) * K + kt + scol,
                        &Asl[buf][ch * 512]);
        }
        #pragma unroll
        for (int i = 0; i < BCW; ++i) {
            const int ch = wave * BCW + i;
            gload_lds16(Bt + (size_t)(col0 + ch * 8 + srow) * K + kt + scol,
                        &Bsl[buf][ch * 512]);
        }
    };

    f32x4 acc[MF][NF];
    #pragma unroll
    for (int m = 0; m < MF; ++m)
        #pragma unroll
        for (int n = 0; n < NF; ++n)
            acc[m][n] = (f32x4){0.f, 0.f, 0.f, 0.f};

    const int nk = K >> 6;

    // prologue: stage tiles 0 and 1, wait for tile 0 only.
    stage(0, 0);
    if (nk > 1) { stage(1, 64); waitcnt_vm<LOADS>(); }
    else        { waitcnt_vm<0>(); }
    __builtin_amdgcn_s_barrier();

    for (int kt = 0; kt < nk; ++kt) {
        __builtin_amdgcn_sched_barrier(0);
        if (kt + 2 < nk) stage((kt + 2) % 3, (kt + 2) << 6);
        __builtin_amdgcn_sched_barrier(0);

        const int cur = kt % 3;
        short8 af[MF][2], bf[NF][2];
        const int lrow  = lane & 15;
        const int xsw   = (lane & 7) * 8;                // read-side XOR
        const int cbase = (lane >> 4) * 8;
        #pragma unroll
        for (int m = 0; m < MF; ++m)
            #pragma unroll
            for (int kk = 0; kk < 2; ++kk)
                af[m][kk] = *(const short8*)
                    &Asl[cur][(wr + m * 16 + lrow) * 64 + ((kk * 32 + cbase) ^ xsw)];
        #pragma unroll
        for (int n = 0; n < NF; ++n)
            #pragma unroll
            for (int kk = 0; kk < 2; ++kk)
                bf[n][kk] = *(const short8*)
                    &Bsl[cur][(wc + n * 16 + lrow) * 64 + ((kk * 32 + cbase) ^ xsw)];

        #pragma unroll
        for (int m = 0; m < MF; ++m)
            #pragma unroll
            for (int n = 0; n < NF; ++n) {
                acc[m][n] = __builtin_amdgcn_mfma_f32_16x16x32_bf16(
                    af[m][0], bf[n][0], acc[m][n], 0, 0, 0);
                acc[m][n] = __builtin_amdgcn_mfma_f32_16x16x32_bf16(
                    af[m][1], bf[n][1], acc[m][n], 0, 0, 0);
            }

        if (kt + 1 < nk) {
            __builtin_amdgcn_sched_barrier(0);
            // wait for tile kt+1 (oldest in flight); leave kt+2's loads flying.
            if (kt + 2 < nk) waitcnt_vm<LOADS>();
            else             waitcnt_vm<0>();
            __builtin_amdgcn_s_barrier();
        }
    }
    __builtin_amdgcn_sched_barrier(0);

    // epilogue: C/D layout col=lane&15, row=(lane>>4)*4+j
    const int crow = (lane >> 4) * 4;
    const int ccol = lane & 15;
    #pragma unroll
    for (int m = 0; m < MF; ++m)
        #pragma unroll
        for (int n = 0; n < NF; ++n) {
            const int c = col0 + wc + n * 16 + ccol;
            if (MODE == 0) {
                const float bv = b0[c];
                unsigned short* dst = (c < NS) ? (U0 + c) : (U1 + (c - NS));
                #pragma unroll
                for (int j = 0; j < 4; ++j) {
                    const int r = row0 + wr + m * 16 + crow + j;
                    dst[(size_t)r * NS] = f2b(acc[m][n][j] + bv);
                }
            } else if (MODE == 1) {
                if (c < 2048) {
                    const float bv = b0[c];
                    #pragma unroll
                    for (int j = 0; j < 4; ++j) {
                        const int r = row0 + wr + m * 16 + crow + j;
                        float v = acc[m][n][j] + bv;
                        v = (v > 20.0f) ? v : log1pf(__expf(v));
                        F0[(size_t)r * 2048 + c] = v;
                    }
                } else if (c < 2064) {
                    const float bv = b1[c - 2048];
                    #pragma unroll
                    for (int j = 0; j < 4; ++j) {
                        const int r = row0 + wr + m * 16 + crow + j;
                        F1[(size_t)r * 16 + (c - 2048)] = acc[m][n][j] + bv;
                    }
                } else if (c < 2080) {
                    const float bv = b2[c - 2064];
                    #pragma unroll
                    for (int j = 0; j < 4; ++j) {
                        const int r = row0 + wr + m * 16 + crow + j;
                        F2[(size_t)r * 16 + (c - 2064)] = acc[m][n][j] + bv;
                    }
                }   // pad columns: discard
            } else {
                const float bv = b0[c];
                #pragma unroll
                for (int j = 0; j < 4; ++j) {
                    const int r = row0 + wr + m * 16 + crow + j;
                    F0[(size_t)r * NS + c] = acc[m][n][j] + bv;
                }
            }
        }
}

// ---------------------------------------------------------------------------
// Depthwise conv (window 4, SAME: taps t-1..t+2) + bias + SiLU.
// Reads bf16 xzb [M][DI]; writes bf16 xcb only.
// ---------------------------------------------------------------------------
__global__ __launch_bounds__(256) void conv_silu(
    const unsigned short* __restrict__ xzb, const float* __restrict__ cw,
    const float* __restrict__ cb, unsigned short* __restrict__ xcb)
{
    const int idx = blockIdx.x * 256 + threadIdx.x;
    if (idx >= BN_ * L_ * DI_) return;
    const int d = idx & (DI_ - 1);
    const int t = (idx / DI_) & (L_ - 1);
    const int b = idx / (DI_ * L_);

    float acc = cb[d];
    #pragma unroll
    for (int w = 0; w < 4; ++w) {
        const int tt = t + w - 1;
        if (tt >= 0 && tt < L_)
            acc = fmaf(b2f(xzb[((size_t)(b * L_ + tt)) * DI_ + d]), cw[w * DI_ + d], acc);
    }
    const float s = acc / (1.0f + __expf(-acc));
    xcb[idx] = f2b(s);
}

// ---------------------------------------------------------------------------
// Chunked selective scan, one CHANNEL per lane, 16 states in registers.
// ---------------------------------------------------------------------------
#define NCH_ 32
#define TL_  (L_ / NCH_)   // 32

__global__ __launch_bounds__(256) void scan_part1(
    const float* __restrict__ dt, const unsigned short* __restrict__ xcb,
    const float* __restrict__ Bm, const float* __restrict__ A,
    float* __restrict__ Pc, float* __restrict__ Hc)
{
    const int tid = threadIdx.x;
    const int d   = blockIdx.x * 256 + tid;
    const int b   = blockIdx.y;
    const int j   = blockIdx.z;
    const int t0  = j * TL_;

    __shared__ float s_Bm[TL_ * DS_];                  // 2 KB
    {
        const float* src = Bm + ((size_t)b * L_ + t0) * DS_;
        s_Bm[tid]       = src[tid];
        s_Bm[256 + tid] = src[256 + tid];
    }
    float a[DS_];
    #pragma unroll
    for (int qq = 0; qq < 4; ++qq)
        *(float4*)&a[qq * 4] = *(const float4*)(A + (size_t)d * DS_ + qq * 4);
    __syncthreads();

    const float* dtp = dt + ((size_t)b * L_ + t0) * DI_ + d;
    const unsigned short* xcp = xcb + ((size_t)b * L_ + t0) * DI_ + d;

    float h[DS_] = {};
    float P[DS_];
    #pragma unroll
    for (int s = 0; s < DS_; ++s) P[s] = 1.0f;

    float dtv = dtp[0], xcv = b2f(xcp[0]);
    #pragma unroll 4
    for (int t = 0; t < TL_; ++t) {
        float dtv_n = 0.f, xcv_n = 0.f;
        if (t + 1 < TL_) {
            dtv_n = dtp[(size_t)(t + 1) * DI_];
            xcv_n = b2f(xcp[(size_t)(t + 1) * DI_]);
        }
        const float dx = dtv * xcv;
        #pragma unroll
        for (int qq = 0; qq < 4; ++qq) {
            const float4 bm = *(const float4*)&s_Bm[t * DS_ + qq * 4];
            #pragma unroll
            for (int i = 0; i < 4; ++i) {
                const int s = qq * 4 + i;
                const float bv = (i == 0) ? bm.x : (i == 1) ? bm.y : (i == 2) ? bm.z : bm.w;
                const float dA = __expf(dtv * a[s]);
                P[s] *= dA;
                h[s] = fmaf(dA, h[s], dx * bv);
            }
        }
        dtv = dtv_n; xcv = xcv_n;
    }
    const size_t o0 = (((size_t)b * NCH_ + j) * DS_) * DI_ + d;
    #pragma unroll
    for (int s = 0; s < DS_; ++s) {
        Pc[o0 + (size_t)s * DI_] = P[s];
        Hc[o0 + (size_t)s * DI_] = h[s];
    }
}

__global__ __launch_bounds__(256) void scan_combine(
    const float* __restrict__ Pc, float* __restrict__ Hc)
{
    const size_t idx = (size_t)blockIdx.x * 256 + threadIdx.x;   // over BN*DS*DI
    const size_t b   = idx / (DS_ * DI_);
    const size_t rem = idx % (DS_ * DI_);
    const size_t base   = b * ((size_t)NCH_ * DS_ * DI_) + rem;
    const size_t stride = (size_t)DS_ * DI_;
    float h = 0.f;
    #pragma unroll
    for (int j = 0; j < NCH_; ++j) {
        const size_t o = base + (size_t)j * stride;
        const float P  = Pc[o];
        const float hl = Hc[o];
        Hc[o] = h;                 // incoming state for chunk j
        h = fmaf(P, h, hl);
    }
}

__global__ __launch_bounds__(256) void scan_part2(
    const float* __restrict__ dt, const unsigned short* __restrict__ xcb,
    const unsigned short* __restrict__ gate,     // bf16
    const float* __restrict__ Bm, const float* __restrict__ Cm,
    const float* __restrict__ A, const float* __restrict__ Dp,
    const float* __restrict__ Hin, unsigned short* __restrict__ ygb)
{
    const int tid = threadIdx.x;
    const int d   = blockIdx.x * 256 + tid;
    const int b   = blockIdx.y;
    const int j   = blockIdx.z;
    const int t0  = j * TL_;

    __shared__ float s_Bm[TL_ * DS_];
    __shared__ float s_Cm[TL_ * DS_];
    {
        const float* bsrc = Bm + ((size_t)b * L_ + t0) * DS_;
        const float* csrc = Cm + ((size_t)b * L_ + t0) * DS_;
        s_Bm[tid]       = bsrc[tid];
        s_Bm[256 + tid] = bsrc[256 + tid];
        s_Cm[tid]       = csrc[tid];
        s_Cm[256 + tid] = csrc[256 + tid];
    }
    float a[DS_];
    #pragma unroll
    for (int qq = 0; qq < 4; ++qq)
        *(float4*)&a[qq * 4] = *(const float4*)(A + (size_t)d * DS_ + qq * 4);
    const float dp = Dp[d];

    float h[DS_];
    {
        const size_t o0 = (((size_t)b * NCH_ + j) * DS_) * DI_ + d;
        #pragma unroll
        for (int s = 0; s < DS_; ++s) h[s] = Hin[o0 + (size_t)s * DI_];
    }
    __syncthreads();

    const size_t rbase = ((size_t)b * L_ + t0) * DI_ + d;
    const float* dtp = dt   + rbase;
    const unsigned short* xcp = xcb + rbase;
    const unsigned short* gvp = gate + rbase;
    unsigned short* yp = ygb + rbase;

    float dtv = dtp[0], xcv = b2f(xcp[0]), gv = b2f(gvp[0]);
    #pragma unroll 4
    for (int t = 0; t < TL_; ++t) {
        float dtv_n = 0.f, xcv_n = 0.f, gv_n = 0.f;
        if (t + 1 < TL_) {
            dtv_n = dtp[(size_t)(t + 1) * DI_];
            xcv_n = b2f(xcp[(size_t)(t + 1) * DI_]);
            gv_n  = b2f(gvp[(size_t)(t + 1) * DI_]);
        }
        const float dx = dtv * xcv;
        float y0 = 0.f, y1 = 0.f, y2 = 0.f, y3 = 0.f;
        #pragma unroll
        for (int qq = 0; qq < 4; ++qq) {
            const float4 bm = *(const float4*)&s_Bm[t * DS_ + qq * 4];
            const float4 cm = *(const float4*)&s_Cm[t * DS_ + qq * 4];
            #pragma unroll
            for (int i = 0; i < 4; ++i) {
                const int s = qq * 4 + i;
                const float bv = (i == 0) ? bm.x : (i == 1) ? bm.y : (i == 2) ? bm.z : bm.w;
                const float cv = (i == 0) ? cm.x : (i == 1) ? cm.y : (i == 2) ? cm.z : cm.w;
                const float dA = __expf(dtv * a[s]);
                h[s] = fmaf(dA, h[s], dx * bv);
                if (i == 0) y0 = fmaf(h[s], cv, y0);
                else if (i == 1) y1 = fmaf(h[s], cv, y1);
                else if (i == 2) y2 = fmaf(h[s], cv, y2);
                else y3 = fmaf(h[s], cv, y3);
            }
        }
        float y = (y0 + y1) + (y2 + y3);
        y = fmaf(xcv, dp, y);
        const float r = y * (gv / (1.0f + __expf(-gv)));
        yp[(size_t)t * DI_] = f2b(r);
        dtv = dtv_n; xcv = xcv_n; gv = gv_n;
    }
}

// ---------------------------------------------------------------------------
extern "C" void kernel_launch(void* const* d_in, const int* in_sizes, int n_in,
                              void* d_out, int out_size, void* d_ws, size_t ws_size,
                              hipStream_t stream)
{
    const float* x      = (const float*)d_in[0];
    const float* in_w   = (const float*)d_in[1];
    const float* in_b   = (const float*)d_in[2];
    const float* conv_w = (const float*)d_in[3];
    const float* conv_b = (const float*)d_in[4];
    const float* A      = (const float*)d_in[5];
    const float* Dp     = (const float*)d_in[6];
    const float* B_w    = (const float*)d_in[7];
    const float* B_b    = (const float*)d_in[8];
    const float* C_w    = (const float*)d_in[9];
    const float* C_b    = (const float*)d_in[10];
    const float* dt_w   = (const float*)d_in[11];
    const float* dt_b   = (const float*)d_in[12];
    const float* out_w  = (const float*)d_in[13];
    const float* out_b  = (const float*)d_in[14];
    float* out = (float*)d_out;

    // ---- workspace layout (aliased; peak 64.75 MB) ----
    float* dtb  = (float*)d_ws;                    // [M][DI] fp32, 16MB
    float* Bm   = dtb + (size_t)M_ * DI_;          // [M][16] 128KB
    float* Cm   = Bm  + (size_t)M_ * DS_;          // [M][16] 128KB
    unsigned short* w3  = (unsigned short*)(Cm + (size_t)M_ * DS_); // out_w^T  4MB
    unsigned short* w1  = w3  + (size_t)DM_ * DI_;                  // in_w^T   8MB
    unsigned short* xb  = w1  + (size_t)2 * DI_ * DM_;              // x bf16   4MB
    unsigned short* w2  = xb  + (size_t)M_ * DM_;                   // dtBC^T   8.5MB
    unsigned short* xcb = w2  + (size_t)NBC_ * DI_;                 // xc bf16  8MB
    unsigned short* xzb = xcb + (size_t)M_ * DI_;                   // xz bf16  8MB
    unsigned short* gtb = xzb + (size_t)M_ * DI_;                   // gate bf16 8MB
    unsigned short* ygb = xcb;                     // alias: p2 reads/writes same offsets
    float* Pc = (float*)w1;                        // 8MB over w1 (dead after in_proj)
    float* Hc = (float*)xb;                        // 8MB over xb + w2 head (dead after dtBC GEMM)

    // 1) bf16 shadows: x, in_w^T
    cast_bf16<<<(M_ * DM_ / 4 + 255) / 256, 256, 0, stream>>>(x, xb, M_ * DM_);
    transpose_cast<<<dim3(2 * DI_ / 32, DM_ / 32), 256, 0, stream>>>(in_w, w1, DM_, 2 * DI_);

    // 2) [xzb | gtb] = bf16(x @ in_w + in_b)   (M=2048, N=4096, K=1024)
    gemm_mfma<64, 128, 0><<<dim3(2 * DI_ / 128, M_ / 64), 256, 0, stream>>>(
        xb, w1, in_b, nullptr, nullptr,
        nullptr, nullptr, nullptr, xzb, gtb, M_, 2 * DI_, DM_, DI_);

    // 3) depthwise conv + silu (bf16 xcb)
    conv_silu<<<(BN_ * L_ * DI_) / 256, 256, 0, stream>>>(xzb, conv_w, conv_b, xcb);

    // 4) fused dt/B/C weights: w2 = [dt_w | B_w | C_w]^T
    transpose_cast<<<dim3(DI_ / 32, DI_ / 32), 256, 0, stream>>>(dt_w, w2, DI_, DI_);
    bc_pack<<<(32 * 2048) / 256, 256, 0, stream>>>(B_w, C_w, w2);

    // 5) dtb = softplus(xc @ dt_w + dt_b); Bm = xc@B_w+B_b; Cm = xc@C_w+C_b
    gemm_mfma<64, 128, 1><<<dim3(NBC_ / 128, M_ / 64), 256, 0, stream>>>(
        xcb, w2, dt_b, B_b, C_b,
        dtb, Bm, Cm, nullptr, nullptr, M_, NBC_, DI_, NBC_);

    // 6) out_w^T
    transpose_cast<<<dim3(DM_ / 32, DI_ / 32), 256, 0, stream>>>(out_w, w3, DI_, DM_);

    // 7) chunked scan: part1 -> combine -> part2 (writes bf16 ygb)
    scan_part1<<<dim3(DI_ / 256, BN_, NCH_), 256, 0, stream>>>(
        dtb, xcb, Bm, A, Pc, Hc);
    scan_combine<<<(BN_ * DI_ * DS_) / 256, 256, 0, stream>>>(Pc, Hc);
    scan_part2<<<dim3(DI_ / 256, BN_, NCH_), 256, 0, stream>>>(
        dtb, xcb, gtb, Bm, Cm, A, Dp, Hc, ygb);

    // 8) out = yg @ out_w + out_b   (M=2048, N=1024, K=2048)
    gemm_mfma<64, 64, 2><<<dim3(DM_ / 64, M_ / 64), 256, 0, stream>>>(
        ygb, w3, out_b, nullptr, nullptr,
        out, nullptr, nullptr, nullptr, nullptr, M_, DM_, DI_, DM_);
}

// Round 10
// 214.357 us; speedup vs baseline: 1.0307x; 1.0307x over previous
//
#include <hip/hip_runtime.h>
#include <hip/hip_bf16.h>
#include <math.h>

// Problem constants: BN=2, L=1024, DM=1024, D_STATE=16, D_CONV=4, EXPAND=2,
// D_INNER=2048. M = BN*L = 2048.
#define BN_   2
#define L_    1024
#define DM_   1024
#define DS_   16
#define DI_   2048
#define M_    (BN_ * L_)
#define NBC_  2176           // dt(2048) + Bm(16) + Cm(16) + pad(96), 17*128

typedef __attribute__((ext_vector_type(8))) short short8;
typedef __attribute__((ext_vector_type(4))) float f32x4;

__device__ __forceinline__ unsigned short f2b(float f) {
    union { float f; unsigned u; } x; x.f = f;
    unsigned r = x.u + 0x7fffu + ((x.u >> 16) & 1u);   // RNE
    return (unsigned short)(r >> 16);
}
__device__ __forceinline__ float b2f(unsigned short u) {
    union { unsigned u; float f; } x; x.u = ((unsigned)u) << 16; return x.f;
}

__device__ __forceinline__ void gload_lds16(const unsigned short* g, unsigned short* l) {
    __builtin_amdgcn_global_load_lds(
        (const __attribute__((address_space(1))) void*)g,
        (__attribute__((address_space(3))) void*)l, 16, 0, 0);
}

// counted vmcnt wait (T4): wait until at most N VMEM ops outstanding.
template<int N> __device__ __forceinline__ void waitcnt_vm() {
    if constexpr (N == 0)      asm volatile("s_waitcnt vmcnt(0)" ::: "memory");
    else if constexpr (N == 4) asm volatile("s_waitcnt vmcnt(4)" ::: "memory");
    else if constexpr (N == 6) asm volatile("s_waitcnt vmcnt(6)" ::: "memory");
    else static_assert(N == 0 || N == 4 || N == 6, "unsupported vmcnt");
}

// ---------------------------------------------------------------------------
// elementwise fp32 -> bf16 cast (n multiple of 4)
// ---------------------------------------------------------------------------
__global__ __launch_bounds__(256) void cast_bf16(
    const float* __restrict__ in, unsigned short* __restrict__ out, int n)
{
    const int i = (blockIdx.x * 256 + threadIdx.x) * 4;
    if (i >= n) return;
    float4 v = *(const float4*)(in + i);
    ushort4 o; o.x = f2b(v.x); o.y = f2b(v.y); o.z = f2b(v.z); o.w = f2b(v.w);
    *(ushort4*)(out + i) = o;
}

// ---------------------------------------------------------------------------
// transpose + cast: in fp32 [R][C] -> out bf16 [C][R].  R,C multiples of 32.
// ---------------------------------------------------------------------------
__global__ __launch_bounds__(256) void transpose_cast(
    const float* __restrict__ in, unsigned short* __restrict__ out, int R, int C)
{
    __shared__ float t[32][33];
    const int bx = blockIdx.x * 32;   // C dir
    const int by = blockIdx.y * 32;   // R dir
    const int tx = threadIdx.x & 31;
    const int ty = (threadIdx.x >> 5) * 4;
    #pragma unroll
    for (int j = 0; j < 4; ++j)
        t[ty + j][tx] = in[(size_t)(by + ty + j) * C + bx + tx];
    __syncthreads();
    #pragma unroll
    for (int j = 0; j < 4; ++j)
        out[(size_t)(bx + ty + j) * R + by + tx] = f2b(t[tx][ty + j]);
}

// ---------------------------------------------------------------------------
// pack B_w / C_w transposed into w2 rows 2048..2079 ([N][K] layout).
// ---------------------------------------------------------------------------
__global__ __launch_bounds__(256) void bc_pack(
    const float* __restrict__ Bw, const float* __restrict__ Cw,
    unsigned short* __restrict__ w2)
{
    const int idx = blockIdx.x * 256 + threadIdx.x;   // 32*2048
    const int r = idx >> 11;        // 0..31
    const int k = idx & 2047;
    const float* src = (r < 16) ? Bw : Cw;
    w2[(size_t)(2048 + r) * 2048 + k] = f2b(src[k * 16 + (r & 15)]);
}

// ---------------------------------------------------------------------------
// bf16 MFMA GEMM, 3-stage counted-vmcnt pipeline (T3+T4, NO sched_barrier
// pinning — R9's regression was m141-style order-pinning + 2 blocks/CU).
// Per iter: stage(k+2) -> ds_read(k)+MFMA -> s_waitcnt vmcnt(LOADS) ->
// s_barrier. Tile k+1's loads get ~2 compute phases in flight before being
// waited; tile k+2's stay flying across the barrier. ds_reads are consumed
// by MFMA data-deps before each barrier (lgkm drained), so overwrite of
// buf (k+2)%3 == (k-1)%3 is safe. Read-side XOR swizzle + XCD block swizzle
// retained.
//   MODE 0: bf16 output, column-split at NS -> U0 | U1        (in_proj)
//   MODE 1: c<2048 softplus -> bf16 U0; 2048..2063 -> F1(+b1) fp32;
//           2064..2079 -> F2(+b2) fp32; pad discarded          (dt+B+C)
//   MODE 2: fp32 single output F0                              (out_proj)
// ---------------------------------------------------------------------------
template<int BM, int BN, int MODE>
__global__ __launch_bounds__(256) void gemm_mfma(
    const unsigned short* __restrict__ A,   // [M][K] bf16
    const unsigned short* __restrict__ Bt,  // [N][K] bf16
    const float* __restrict__ b0, const float* __restrict__ b1,
    const float* __restrict__ b2,
    float* __restrict__ F0, float* __restrict__ F1, float* __restrict__ F2,
    unsigned short* __restrict__ U0, unsigned short* __restrict__ U1,
    int M, int N, int K, int NS)
{
    constexpr int MF    = BM / 32;            // m-frags per wave
    constexpr int NF    = BN / 32;            // n-frags per wave
    constexpr int ACW   = BM / 32;            // A 8-row chunks per wave per stage
    constexpr int BCW   = BN / 32;            // B 8-row chunks per wave per stage
    constexpr int LOADS = ACW + BCW;          // VMEM ops per wave per stage

    __shared__ unsigned short Asl[3][BM * 64];
    __shared__ unsigned short Bsl[3][BN * 64];

    const int tid  = threadIdx.x;
    const int wave = tid >> 6;
    const int lane = tid & 63;

    // XCD-aware bijective swizzle (all call sites have nwg % 8 == 0).
    const int gx  = gridDim.x, gy = gridDim.y;
    const int bid = blockIdx.y * gx + blockIdx.x;
    const int q   = (gx * gy) >> 3;
    const int nb  = (bid & 7) * q + (bid >> 3);
    const int by  = nb % gy;
    const int bx  = nb / gy;

    const int row0 = by * BM;
    const int col0 = bx * BN;
    const int wr   = (wave >> 1) * (BM / 2);
    const int wc   = (wave & 1) * (BN / 2);

    const int srow = lane >> 3;                          // row within 8-row chunk
    const int scol = ((lane & 7) ^ (lane >> 3)) * 8;     // pre-swizzled source col

    auto stage = [&](int buf, int kt) {
        #pragma unroll
        for (int i = 0; i < ACW; ++i) {
            const int ch = wave * ACW + i;
            gload_lds16(A + (size_t)(row0 + ch * 8 + srow) * K + kt + scol,
                        &Asl[buf][ch * 512]);
        }
        #pragma unroll
        for (int i = 0; i < BCW; ++i) {
            const int ch = wave * BCW + i;
            gload_lds16(Bt + (size_t)(col0 + ch * 8 + srow) * K + kt + scol,
                        &Bsl[buf][ch * 512]);
        }
    };

    f32x4 acc[MF][NF];
    #pragma unroll
    for (int m = 0; m < MF; ++m)
        #pragma unroll
        for (int n = 0; n < NF; ++n)
            acc[m][n] = (f32x4){0.f, 0.f, 0.f, 0.f};

    const int nk = K >> 6;

    // prologue: stage tiles 0 and 1; wait only for tile 0.
    stage(0, 0);
    if (nk > 1) { stage(1, 64); waitcnt_vm<LOADS>(); }
    else        { waitcnt_vm<0>(); }
    __builtin_amdgcn_s_barrier();

    int cur = 0;
    for (int kt = 0; kt < nk; ++kt) {
        if (kt + 2 < nk) {
            int nxt = cur + 2; if (nxt >= 3) nxt -= 3;
            stage(nxt, (kt + 2) << 6);
        }

        short8 af[MF][2], bf[NF][2];
        const int lrow  = lane & 15;
        const int xsw   = (lane & 7) * 8;                // read-side XOR
        const int cbase = (lane >> 4) * 8;
        #pragma unroll
        for (int m = 0; m < MF; ++m)
            #pragma unroll
            for (int kk = 0; kk < 2; ++kk)
                af[m][kk] = *(const short8*)
                    &Asl[cur][(wr + m * 16 + lrow) * 64 + ((kk * 32 + cbase) ^ xsw)];
        #pragma unroll
        for (int n = 0; n < NF; ++n)
            #pragma unroll
            for (int kk = 0; kk < 2; ++kk)
                bf[n][kk] = *(const short8*)
                    &Bsl[cur][(wc + n * 16 + lrow) * 64 + ((kk * 32 + cbase) ^ xsw)];

        #pragma unroll
        for (int m = 0; m < MF; ++m)
            #pragma unroll
            for (int n = 0; n < NF; ++n) {
                acc[m][n] = __builtin_amdgcn_mfma_f32_16x16x32_bf16(
                    af[m][0], bf[n][0], acc[m][n], 0, 0, 0);
                acc[m][n] = __builtin_amdgcn_mfma_f32_16x16x32_bf16(
                    af[m][1], bf[n][1], acc[m][n], 0, 0, 0);
            }

        if (kt + 1 < nk) {
            // wait tile kt+1 (oldest in flight); leave kt+2's loads flying.
            if (kt + 2 < nk) waitcnt_vm<LOADS>();
            else             waitcnt_vm<0>();
            __builtin_amdgcn_s_barrier();
        }
        ++cur; if (cur >= 3) cur -= 3;
    }

    // epilogue: C/D layout col=lane&15, row=(lane>>4)*4+j
    const int crow = (lane >> 4) * 4;
    const int ccol = lane & 15;
    #pragma unroll
    for (int m = 0; m < MF; ++m)
        #pragma unroll
        for (int n = 0; n < NF; ++n) {
            const int c = col0 + wc + n * 16 + ccol;
            if (MODE == 0) {
                const float bv = b0[c];
                unsigned short* dst = (c < NS) ? (U0 + c) : (U1 + (c - NS));
                #pragma unroll
                for (int j = 0; j < 4; ++j) {
                    const int r = row0 + wr + m * 16 + crow + j;
                    dst[(size_t)r * NS] = f2b(acc[m][n][j] + bv);
                }
            } else if (MODE == 1) {
                if (c < 2048) {
                    const float bv = b0[c];
                    #pragma unroll
                    for (int j = 0; j < 4; ++j) {
                        const int r = row0 + wr + m * 16 + crow + j;
                        float v = acc[m][n][j] + bv;
                        v = (v > 20.0f) ? v : log1pf(__expf(v));
                        U0[(size_t)r * 2048 + c] = f2b(v);
                    }
                } else if (c < 2064) {
                    const float bv = b1[c - 2048];
                    #pragma unroll
                    for (int j = 0; j < 4; ++j) {
                        const int r = row0 + wr + m * 16 + crow + j;
                        F1[(size_t)r * 16 + (c - 2048)] = acc[m][n][j] + bv;
                    }
                } else if (c < 2080) {
                    const float bv = b2[c - 2064];
                    #pragma unroll
                    for (int j = 0; j < 4; ++j) {
                        const int r = row0 + wr + m * 16 + crow + j;
                        F2[(size_t)r * 16 + (c - 2064)] = acc[m][n][j] + bv;
                    }
                }   // pad columns: discard
            } else {
                const float bv = b0[c];
                #pragma unroll
                for (int j = 0; j < 4; ++j) {
                    const int r = row0 + wr + m * 16 + crow + j;
                    F0[(size_t)r * NS + c] = acc[m][n][j] + bv;
                }
            }
        }
}

// ---------------------------------------------------------------------------
// Depthwise conv (window 4, SAME: taps t-1..t+2) + bias + SiLU.
// Reads bf16 xzb [M][DI]; writes bf16 xcb only.
// ---------------------------------------------------------------------------
__global__ __launch_bounds__(256) void conv_silu(
    const unsigned short* __restrict__ xzb, const float* __restrict__ cw,
    const float* __restrict__ cb, unsigned short* __restrict__ xcb)
{
    const int idx = blockIdx.x * 256 + threadIdx.x;
    if (idx >= BN_ * L_ * DI_) return;
    const int d = idx & (DI_ - 1);
    const int t = (idx / DI_) & (L_ - 1);
    const int b = idx / (DI_ * L_);

    float acc = cb[d];
    #pragma unroll
    for (int w = 0; w < 4; ++w) {
        const int tt = t + w - 1;
        if (tt >= 0 && tt < L_)
            acc = fmaf(b2f(xzb[((size_t)(b * L_ + tt)) * DI_ + d]), cw[w * DI_ + d], acc);
    }
    const float s = acc / (1.0f + __expf(-acc));
    xcb[idx] = f2b(s);
}

// ---------------------------------------------------------------------------
// Chunked selective scan, one CHANNEL per lane, 16 states in registers.
// dt consumed as bf16.
// ---------------------------------------------------------------------------
#define NCH_ 32
#define TL_  (L_ / NCH_)   // 32

__global__ __launch_bounds__(256) void scan_part1(
    const unsigned short* __restrict__ dt, const unsigned short* __restrict__ xcb,
    const float* __restrict__ Bm, const float* __restrict__ A,
    float* __restrict__ Pc, float* __restrict__ Hc)
{
    const int tid = threadIdx.x;
    const int d   = blockIdx.x * 256 + tid;
    const int b   = blockIdx.y;
    const int j   = blockIdx.z;
    const int t0  = j * TL_;

    __shared__ float s_Bm[TL_ * DS_];                  // 2 KB
    {
        const float* src = Bm + ((size_t)b * L_ + t0) * DS_;
        s_Bm[tid]       = src[tid];
        s_Bm[256 + tid] = src[256 + tid];
    }
    float a[DS_];
    #pragma unroll
    for (int qq = 0; qq < 4; ++qq)
        *(float4*)&a[qq * 4] = *(const float4*)(A + (size_t)d * DS_ + qq * 4);
    __syncthreads();

    const unsigned short* dtp = dt + ((size_t)b * L_ + t0) * DI_ + d;
    const unsigned short* xcp = xcb + ((size_t)b * L_ + t0) * DI_ + d;

    float h[DS_] = {};
    float P[DS_];
    #pragma unroll
    for (int s = 0; s < DS_; ++s) P[s] = 1.0f;

    float dtv = b2f(dtp[0]), xcv = b2f(xcp[0]);
    #pragma unroll 4
    for (int t = 0; t < TL_; ++t) {
        float dtv_n = 0.f, xcv_n = 0.f;
        if (t + 1 < TL_) {
            dtv_n = b2f(dtp[(size_t)(t + 1) * DI_]);
            xcv_n = b2f(xcp[(size_t)(t + 1) * DI_]);
        }
        const float dx = dtv * xcv;
        #pragma unroll
        for (int qq = 0; qq < 4; ++qq) {
            const float4 bm = *(const float4*)&s_Bm[t * DS_ + qq * 4];
            #pragma unroll
            for (int i = 0; i < 4; ++i) {
                const int s = qq * 4 + i;
                const float bv = (i == 0) ? bm.x : (i == 1) ? bm.y : (i == 2) ? bm.z : bm.w;
                const float dA = __expf(dtv * a[s]);
                P[s] *= dA;
                h[s] = fmaf(dA, h[s], dx * bv);
            }
        }
        dtv = dtv_n; xcv = xcv_n;
    }
    const size_t o0 = (((size_t)b * NCH_ + j) * DS_) * DI_ + d;
    #pragma unroll
    for (int s = 0; s < DS_; ++s) {
        Pc[o0 + (size_t)s * DI_] = P[s];
        Hc[o0 + (size_t)s * DI_] = h[s];
    }
}

__global__ __launch_bounds__(256) void scan_combine(
    const float* __restrict__ Pc, float* __restrict__ Hc)
{
    const size_t idx = (size_t)blockIdx.x * 256 + threadIdx.x;   // over BN*DS*DI
    const size_t b   = idx / (DS_ * DI_);
    const size_t rem = idx % (DS_ * DI_);
    const size_t base   = b * ((size_t)NCH_ * DS_ * DI_) + rem;
    const size_t stride = (size_t)DS_ * DI_;
    float h = 0.f;
    #pragma unroll
    for (int j = 0; j < NCH_; ++j) {
        const size_t o = base + (size_t)j * stride;
        const float P  = Pc[o];
        const float hl = Hc[o];
        Hc[o] = h;                 // incoming state for chunk j
        h = fmaf(P, h, hl);
    }
}

__global__ __launch_bounds__(256) void scan_part2(
    const unsigned short* __restrict__ dt, const unsigned short* __restrict__ xcb,
    const unsigned short* __restrict__ gate,     // bf16
    const float* __restrict__ Bm, const float* __restrict__ Cm,
    const float* __restrict__ A, const float* __restrict__ Dp,
    const float* __restrict__ Hin, unsigned short* __restrict__ ygb)
{
    const int tid = threadIdx.x;
    const int d   = blockIdx.x * 256 + tid;
    const int b   = blockIdx.y;
    const int j   = blockIdx.z;
    const int t0  = j * TL_;

    __shared__ float s_Bm[TL_ * DS_];
    __shared__ float s_Cm[TL_ * DS_];
    {
        const float* bsrc = Bm + ((size_t)b * L_ + t0) * DS_;
        const float* csrc = Cm + ((size_t)b * L_ + t0) * DS_;
        s_Bm[tid]       = bsrc[tid];
        s_Bm[256 + tid] = bsrc[256 + tid];
        s_Cm[tid]       = csrc[tid];
        s_Cm[256 + tid] = csrc[256 + tid];
    }
    float a[DS_];
    #pragma unroll
    for (int qq = 0; qq < 4; ++qq)
        *(float4*)&a[qq * 4] = *(const float4*)(A + (size_t)d * DS_ + qq * 4);
    const float dp = Dp[d];

    float h[DS_];
    {
        const size_t o0 = (((size_t)b * NCH_ + j) * DS_) * DI_ + d;
        #pragma unroll
        for (int s = 0; s < DS_; ++s) h[s] = Hin[o0 + (size_t)s * DI_];
    }
    __syncthreads();

    const size_t rbase = ((size_t)b * L_ + t0) * DI_ + d;
    const unsigned short* dtp = dt   + rbase;
    const unsigned short* xcp = xcb  + rbase;
    const unsigned short* gvp = gate + rbase;
    unsigned short* yp = ygb + rbase;

    float dtv = b2f(dtp[0]), xcv = b2f(xcp[0]), gv = b2f(gvp[0]);
    #pragma unroll 4
    for (int t = 0; t < TL_; ++t) {
        float dtv_n = 0.f, xcv_n = 0.f, gv_n = 0.f;
        if (t + 1 < TL_) {
            dtv_n = b2f(dtp[(size_t)(t + 1) * DI_]);
            xcv_n = b2f(xcp[(size_t)(t + 1) * DI_]);
            gv_n  = b2f(gvp[(size_t)(t + 1) * DI_]);
        }
        const float dx = dtv * xcv;
        float y0 = 0.f, y1 = 0.f, y2 = 0.f, y3 = 0.f;
        #pragma unroll
        for (int qq = 0; qq < 4; ++qq) {
            const float4 bm = *(const float4*)&s_Bm[t * DS_ + qq * 4];
            const float4 cm = *(const float4*)&s_Cm[t * DS_ + qq * 4];
            #pragma unroll
            for (int i = 0; i < 4; ++i) {
                const int s = qq * 4 + i;
                const float bv = (i == 0) ? bm.x : (i == 1) ? bm.y : (i == 2) ? bm.z : bm.w;
                const float cv = (i == 0) ? cm.x : (i == 1) ? cm.y : (i == 2) ? cm.z : cm.w;
                const float dA = __expf(dtv * a[s]);
                h[s] = fmaf(dA, h[s], dx * bv);
                if (i == 0) y0 = fmaf(h[s], cv, y0);
                else if (i == 1) y1 = fmaf(h[s], cv, y1);
                else if (i == 2) y2 = fmaf(h[s], cv, y2);
                else y3 = fmaf(h[s], cv, y3);
            }
        }
        float y = (y0 + y1) + (y2 + y3);
        y = fmaf(xcv, dp, y);
        const float r = y * (gv / (1.0f + __expf(-gv)));
        yp[(size_t)t * DI_] = f2b(r);
        dtv = dtv_n; xcv = xcv_n; gv = gv_n;
    }
}

// ---------------------------------------------------------------------------
extern "C" void kernel_launch(void* const* d_in, const int* in_sizes, int n_in,
                              void* d_out, int out_size, void* d_ws, size_t ws_size,
                              hipStream_t stream)
{
    const float* x      = (const float*)d_in[0];
    const float* in_w   = (const float*)d_in[1];
    const float* in_b   = (const float*)d_in[2];
    const float* conv_w = (const float*)d_in[3];
    const float* conv_b = (const float*)d_in[4];
    const float* A      = (const float*)d_in[5];
    const float* Dp     = (const float*)d_in[6];
    const float* B_w    = (const float*)d_in[7];
    const float* B_b    = (const float*)d_in[8];
    const float* C_w    = (const float*)d_in[9];
    const float* C_b    = (const float*)d_in[10];
    const float* dt_w   = (const float*)d_in[11];
    const float* dt_b   = (const float*)d_in[12];
    const float* out_w  = (const float*)d_in[13];
    const float* out_b  = (const float*)d_in[14];
    float* out = (float*)d_out;

    // ---- workspace layout (aliased) ----
    unsigned short* dtb = (unsigned short*)d_ws;   // [M][DI] bf16, 8MB
    float* Bm   = (float*)(dtb + (size_t)M_ * DI_);          // [M][16] 128KB
    float* Cm   = Bm  + (size_t)M_ * DS_;                    // [M][16] 128KB
    unsigned short* w3  = (unsigned short*)(Cm + (size_t)M_ * DS_); // out_w^T  4MB
    unsigned short* w1  = w3  + (size_t)DM_ * DI_;                  // in_w^T   8MB
    unsigned short* xb  = w1  + (size_t)2 * DI_ * DM_;              // x bf16   4MB
    unsigned short* w2  = xb  + (size_t)M_ * DM_;                   // dtBC^T   8.5MB
    unsigned short* xcb = w2  + (size_t)NBC_ * DI_;                 // xc bf16  8MB
    unsigned short* xzb = xcb + (size_t)M_ * DI_;                   // xz bf16  8MB
    unsigned short* gtb = xzb + (size_t)M_ * DI_;                   // gate bf16 8MB
    unsigned short* ygb = xcb;                     // alias: p2 reads/writes same offsets
    float* Pc = (float*)w1;                        // 8MB over w1 (dead after in_proj)
    float* Hc = (float*)xb;                        // 8MB over xb + w2 head (dead after dtBC GEMM)

    // 1) bf16 shadows: x, in_w^T
    cast_bf16<<<(M_ * DM_ / 4 + 255) / 256, 256, 0, stream>>>(x, xb, M_ * DM_);
    transpose_cast<<<dim3(2 * DI_ / 32, DM_ / 32), 256, 0, stream>>>(in_w, w1, DM_, 2 * DI_);

    // 2) [xzb | gtb] = bf16(x @ in_w + in_b)   (M=2048, N=4096, K=1024)
    gemm_mfma<64, 128, 0><<<dim3(2 * DI_ / 128, M_ / 64), 256, 0, stream>>>(
        xb, w1, in_b, nullptr, nullptr,
        nullptr, nullptr, nullptr, xzb, gtb, M_, 2 * DI_, DM_, DI_);

    // 3) depthwise conv + silu (bf16 xcb)
    conv_silu<<<(BN_ * L_ * DI_) / 256, 256, 0, stream>>>(xzb, conv_w, conv_b, xcb);

    // 4) fused dt/B/C weights: w2 = [dt_w | B_w | C_w]^T
    transpose_cast<<<dim3(DI_ / 32, DI_ / 32), 256, 0, stream>>>(dt_w, w2, DI_, DI_);
    bc_pack<<<(32 * 2048) / 256, 256, 0, stream>>>(B_w, C_w, w2);

    // 5) dtb(bf16) = softplus(xc @ dt_w + dt_b); Bm,Cm fp32
    gemm_mfma<64, 128, 1><<<dim3(NBC_ / 128, M_ / 64), 256, 0, stream>>>(
        xcb, w2, dt_b, B_b, C_b,
        nullptr, Bm, Cm, dtb, nullptr, M_, NBC_, DI_, NBC_);

    // 6) out_w^T
    transpose_cast<<<dim3(DM_ / 32, DI_ / 32), 256, 0, stream>>>(out_w, w3, DI_, DM_);

    // 7) chunked scan: part1 -> combine -> part2 (writes bf16 ygb)
    scan_part1<<<dim3(DI_ / 256, BN_, NCH_), 256, 0, stream>>>(
        dtb, xcb, Bm, A, Pc, Hc);
    scan_combine<<<(BN_ * DI_ * DS_) / 256, 256, 0, stream>>>(Pc, Hc);
    scan_part2<<<dim3(DI_ / 256, BN_, NCH_), 256, 0, stream>>>(
        dtb, xcb, gtb, Bm, Cm, A, Dp, Hc, ygb);

    // 8) out = yg @ out_w + out_b   (M=2048, N=1024, K=2048)
    gemm_mfma<64, 64, 2><<<dim3(DM_ / 64, M_ / 64), 256, 0, stream>>>(
        ygb, w3, out_b, nullptr, nullptr,
        out, nullptr, nullptr, nullptr, nullptr, M_, DM_, DI_, DM_);
}

// Round 11
// 182.822 us; speedup vs baseline: 1.2084x; 1.1725x over previous
//
#include <hip/hip_runtime.h>
#include <hip/hip_bf16.h>
#include <math.h>

// Problem constants: BN=2, L=1024, DM=1024, D_STATE=16, D_CONV=4, EXPAND=2,
// D_INNER=2048. M = BN*L = 2048.
#define BN_   2
#define L_    1024
#define DM_   1024
#define DS_   16
#define DI_   2048
#define M_    (BN_ * L_)
#define NBC_  2176           // dt(2048) + Bm(16) + Cm(16) + pad(96), 17*128

typedef __attribute__((ext_vector_type(8))) short short8;
typedef __attribute__((ext_vector_type(4))) float f32x4;

__device__ __forceinline__ unsigned short f2b(float f) {
    union { float f; unsigned u; } x; x.f = f;
    unsigned r = x.u + 0x7fffu + ((x.u >> 16) & 1u);   // RNE
    return (unsigned short)(r >> 16);
}
__device__ __forceinline__ float b2f(unsigned short u) {
    union { unsigned u; float f; } x; x.u = ((unsigned)u) << 16; return x.f;
}

__device__ __forceinline__ void gload_lds16(const unsigned short* g, unsigned short* l) {
    __builtin_amdgcn_global_load_lds(
        (const __attribute__((address_space(1))) void*)g,
        (__attribute__((address_space(3))) void*)l, 16, 0, 0);
}

// ---------------------------------------------------------------------------
// Fused prep: one dispatch does x->bf16 cast, in_w/dt_w/out_w transpose-cast,
// and B_w/C_w pack. Sections by blockIdx.x (uniform per block -> barriers ok).
//   [0,2048)        : cast x (2M fp32 -> bf16)
//   [2048,6144)     : in_w  [1024][4096] -> w1 [4096][1024]
//   [6144,10240)    : dt_w  [2048][2048] -> w2 [2048][2048]
//   [10240,12288)   : out_w [2048][1024] -> w3 [1024][2048]
//   [12288,12544)   : bc_pack -> w2 rows 2048..2079
// ---------------------------------------------------------------------------
__device__ __forceinline__ void tr_tile(
    const float* __restrict__ in, unsigned short* __restrict__ out,
    int R, int C, int bx, int by)
{
    __shared__ float t[32][33];
    const int tx = threadIdx.x & 31;
    const int ty = (threadIdx.x >> 5) * 4;
    #pragma unroll
    for (int j = 0; j < 4; ++j)
        t[ty + j][tx] = in[(size_t)(by + ty + j) * C + bx + tx];
    __syncthreads();
    #pragma unroll
    for (int j = 0; j < 4; ++j)
        out[(size_t)(bx + ty + j) * R + by + tx] = f2b(t[tx][ty + j]);
}

__global__ __launch_bounds__(256) void prep(
    const float* __restrict__ x,
    const float* __restrict__ in_w, const float* __restrict__ dt_w,
    const float* __restrict__ out_w,
    const float* __restrict__ Bw, const float* __restrict__ Cw,
    unsigned short* __restrict__ xb, unsigned short* __restrict__ w1,
    unsigned short* __restrict__ w2, unsigned short* __restrict__ w3)
{
    const int blk = blockIdx.x;
    const int tid = threadIdx.x;
    if (blk < 2048) {                                   // cast x
        const int i = (blk * 256 + tid) * 4;
        if (i < M_ * DM_) {
            float4 v = *(const float4*)(x + i);
            ushort4 o; o.x = f2b(v.x); o.y = f2b(v.y); o.z = f2b(v.z); o.w = f2b(v.w);
            *(ushort4*)(xb + i) = o;
        }
    } else if (blk < 6144) {                            // in_w^T
        const int id = blk - 2048;
        tr_tile(in_w, w1, DM_, 2 * DI_, (id & 127) * 32, (id >> 7) * 32);
    } else if (blk < 10240) {                           // dt_w^T
        const int id = blk - 6144;
        tr_tile(dt_w, w2, DI_, DI_, (id & 63) * 32, (id >> 6) * 32);
    } else if (blk < 12288) {                           // out_w^T
        const int id = blk - 10240;
        tr_tile(out_w, w3, DI_, DM_, (id & 31) * 32, (id >> 5) * 32);
    } else {                                            // bc_pack
        const int idx = (blk - 12288) * 256 + tid;      // 32*2048
        const int r = idx >> 11;
        const int k = idx & 2047;
        const float* src = (r < 16) ? Bw : Cw;
        w2[(size_t)(2048 + r) * 2048 + k] = f2b(src[k * 16 + (r & 15)]);
    }
}

// ---------------------------------------------------------------------------
// bf16 MFMA GEMM, 2-stage double-buffered (R8 structure — proven best):
// stage(k+1) issued BEFORE compute(k); one __syncthreads per K-step (its
// vmcnt(0) waits on loads that had the whole compute phase in flight).
// Read-side XOR swizzle (bank-conflict-free) + XCD-aware bijective block
// swizzle. Tile BM x BN, BK=64, 4 waves (2x2), 16x16x32 frags.
//   MODE 0: bf16 output, column-split at NS -> U0 | U1        (in_proj)
//   MODE 1: c<2048 softplus -> bf16 U0; 2048..2063 -> F1(+b1) fp32;
//           2064..2079 -> F2(+b2) fp32; pad discarded          (dt+B+C)
//   MODE 2: fp32 single output F0                              (out_proj)
// ---------------------------------------------------------------------------
template<int BM, int BN, int MODE>
__global__ __launch_bounds__(256) void gemm_mfma(
    const unsigned short* __restrict__ A,   // [M][K] bf16
    const unsigned short* __restrict__ Bt,  // [N][K] bf16
    const float* __restrict__ b0, const float* __restrict__ b1,
    const float* __restrict__ b2,
    float* __restrict__ F0, float* __restrict__ F1, float* __restrict__ F2,
    unsigned short* __restrict__ U0, unsigned short* __restrict__ U1,
    int M, int N, int K, int NS)
{
    constexpr int MF  = BM / 32;   // m-frags per wave
    constexpr int NF  = BN / 32;   // n-frags per wave
    constexpr int ACW = BM / 32;   // A 8-row chunks staged per wave
    constexpr int BCW = BN / 32;   // B 8-row chunks staged per wave

    __shared__ unsigned short Asl[2][BM * 64];
    __shared__ unsigned short Bsl[2][BN * 64];

    const int tid  = threadIdx.x;
    const int wave = tid >> 6;
    const int lane = tid & 63;

    // XCD-aware bijective swizzle (all call sites have nwg % 8 == 0).
    const int gx  = gridDim.x, gy = gridDim.y;
    const int bid = blockIdx.y * gx + blockIdx.x;
    const int q   = (gx * gy) >> 3;
    const int nb  = (bid & 7) * q + (bid >> 3);
    const int by  = nb % gy;
    const int bx  = nb / gy;

    const int row0 = by * BM;
    const int col0 = bx * BN;
    const int wr   = (wave >> 1) * (BM / 2);
    const int wc   = (wave & 1) * (BN / 2);

    const int srow = lane >> 3;                          // row within 8-row chunk
    const int scol = ((lane & 7) ^ (lane >> 3)) * 8;     // pre-swizzled source col

    auto stage = [&](int buf, int kt) {
        #pragma unroll
        for (int i = 0; i < ACW; ++i) {
            const int ch = wave * ACW + i;
            gload_lds16(A + (size_t)(row0 + ch * 8 + srow) * K + kt + scol,
                        &Asl[buf][ch * 512]);
        }
        #pragma unroll
        for (int i = 0; i < BCW; ++i) {
            const int ch = wave * BCW + i;
            gload_lds16(Bt + (size_t)(col0 + ch * 8 + srow) * K + kt + scol,
                        &Bsl[buf][ch * 512]);
        }
    };

    f32x4 acc[MF][NF];
    #pragma unroll
    for (int m = 0; m < MF; ++m)
        #pragma unroll
        for (int n = 0; n < NF; ++n)
            acc[m][n] = (f32x4){0.f, 0.f, 0.f, 0.f};

    stage(0, 0);
    __syncthreads();

    const int nk = K >> 6;
    int cur = 0;
    for (int kt = 0; kt < nk; ++kt) {
        if (kt + 1 < nk) stage(cur ^ 1, (kt + 1) << 6);

        short8 af[MF][2], bf[NF][2];
        const int lrow  = lane & 15;
        const int xsw   = (lane & 7) * 8;                // read-side XOR
        const int cbase = (lane >> 4) * 8;
        #pragma unroll
        for (int m = 0; m < MF; ++m)
            #pragma unroll
            for (int kk = 0; kk < 2; ++kk)
                af[m][kk] = *(const short8*)
                    &Asl[cur][(wr + m * 16 + lrow) * 64 + ((kk * 32 + cbase) ^ xsw)];
        #pragma unroll
        for (int n = 0; n < NF; ++n)
            #pragma unroll
            for (int kk = 0; kk < 2; ++kk)
                bf[n][kk] = *(const short8*)
                    &Bsl[cur][(wc + n * 16 + lrow) * 64 + ((kk * 32 + cbase) ^ xsw)];

        #pragma unroll
        for (int m = 0; m < MF; ++m)
            #pragma unroll
            for (int n = 0; n < NF; ++n) {
                acc[m][n] = __builtin_amdgcn_mfma_f32_16x16x32_bf16(
                    af[m][0], bf[n][0], acc[m][n], 0, 0, 0);
                acc[m][n] = __builtin_amdgcn_mfma_f32_16x16x32_bf16(
                    af[m][1], bf[n][1], acc[m][n], 0, 0, 0);
            }
        __syncthreads();   // drains prefetch vmcnt + protects cur from overwrite
        cur ^= 1;
    }

    // epilogue: C/D layout col=lane&15, row=(lane>>4)*4+j
    const int crow = (lane >> 4) * 4;
    const int ccol = lane & 15;
    #pragma unroll
    for (int m = 0; m < MF; ++m)
        #pragma unroll
        for (int n = 0; n < NF; ++n) {
            const int c = col0 + wc + n * 16 + ccol;
            if (MODE == 0) {
                const float bv = b0[c];
                unsigned short* dst = (c < NS) ? (U0 + c) : (U1 + (c - NS));
                #pragma unroll
                for (int j = 0; j < 4; ++j) {
                    const int r = row0 + wr + m * 16 + crow + j;
                    dst[(size_t)r * NS] = f2b(acc[m][n][j] + bv);
                }
            } else if (MODE == 1) {
                if (c < 2048) {
                    const float bv = b0[c];
                    #pragma unroll
                    for (int j = 0; j < 4; ++j) {
                        const int r = row0 + wr + m * 16 + crow + j;
                        float v = acc[m][n][j] + bv;
                        v = (v > 20.0f) ? v : log1pf(__expf(v));
                        U0[(size_t)r * 2048 + c] = f2b(v);
                    }
                } else if (c < 2064) {
                    const float bv = b1[c - 2048];
                    #pragma unroll
                    for (int j = 0; j < 4; ++j) {
                        const int r = row0 + wr + m * 16 + crow + j;
                        F1[(size_t)r * 16 + (c - 2048)] = acc[m][n][j] + bv;
                    }
                } else if (c < 2080) {
                    const float bv = b2[c - 2064];
                    #pragma unroll
                    for (int j = 0; j < 4; ++j) {
                        const int r = row0 + wr + m * 16 + crow + j;
                        F2[(size_t)r * 16 + (c - 2064)] = acc[m][n][j] + bv;
                    }
                }   // pad columns: discard
            } else {
                const float bv = b0[c];
                #pragma unroll
                for (int j = 0; j < 4; ++j) {
                    const int r = row0 + wr + m * 16 + crow + j;
                    F0[(size_t)r * NS + c] = acc[m][n][j] + bv;
                }
            }
        }
}

// ---------------------------------------------------------------------------
// Depthwise conv (window 4, SAME: taps t-1..t+2) + bias + SiLU.
// Reads bf16 xzb [M][DI]; writes bf16 xcb only.
// ---------------------------------------------------------------------------
__global__ __launch_bounds__(256) void conv_silu(
    const unsigned short* __restrict__ xzb, const float* __restrict__ cw,
    const float* __restrict__ cb, unsigned short* __restrict__ xcb)
{
    const int idx = blockIdx.x * 256 + threadIdx.x;
    if (idx >= BN_ * L_ * DI_) return;
    const int d = idx & (DI_ - 1);
    const int t = (idx / DI_) & (L_ - 1);
    const int b = idx / (DI_ * L_);

    float acc = cb[d];
    #pragma unroll
    for (int w = 0; w < 4; ++w) {
        const int tt = t + w - 1;
        if (tt >= 0 && tt < L_)
            acc = fmaf(b2f(xzb[((size_t)(b * L_ + tt)) * DI_ + d]), cw[w * DI_ + d], acc);
    }
    const float s = acc / (1.0f + __expf(-acc));
    xcb[idx] = f2b(s);
}

// ---------------------------------------------------------------------------
// Chunked selective scan, one CHANNEL per lane, 16 states in registers.
// dt consumed as bf16.
// ---------------------------------------------------------------------------
#define NCH_ 32
#define TL_  (L_ / NCH_)   // 32

__global__ __launch_bounds__(256) void scan_part1(
    const unsigned short* __restrict__ dt, const unsigned short* __restrict__ xcb,
    const float* __restrict__ Bm, const float* __restrict__ A,
    float* __restrict__ Pc, float* __restrict__ Hc)
{
    const int tid = threadIdx.x;
    const int d   = blockIdx.x * 256 + tid;
    const int b   = blockIdx.y;
    const int j   = blockIdx.z;
    const int t0  = j * TL_;

    __shared__ float s_Bm[TL_ * DS_];                  // 2 KB
    {
        const float* src = Bm + ((size_t)b * L_ + t0) * DS_;
        s_Bm[tid]       = src[tid];
        s_Bm[256 + tid] = src[256 + tid];
    }
    float a[DS_];
    #pragma unroll
    for (int qq = 0; qq < 4; ++qq)
        *(float4*)&a[qq * 4] = *(const float4*)(A + (size_t)d * DS_ + qq * 4);
    __syncthreads();

    const unsigned short* dtp = dt + ((size_t)b * L_ + t0) * DI_ + d;
    const unsigned short* xcp = xcb + ((size_t)b * L_ + t0) * DI_ + d;

    float h[DS_] = {};
    float P[DS_];
    #pragma unroll
    for (int s = 0; s < DS_; ++s) P[s] = 1.0f;

    float dtv = b2f(dtp[0]), xcv = b2f(xcp[0]);
    #pragma unroll 4
    for (int t = 0; t < TL_; ++t) {
        float dtv_n = 0.f, xcv_n = 0.f;
        if (t + 1 < TL_) {
            dtv_n = b2f(dtp[(size_t)(t + 1) * DI_]);
            xcv_n = b2f(xcp[(size_t)(t + 1) * DI_]);
        }
        const float dx = dtv * xcv;
        #pragma unroll
        for (int qq = 0; qq < 4; ++qq) {
            const float4 bm = *(const float4*)&s_Bm[t * DS_ + qq * 4];
            #pragma unroll
            for (int i = 0; i < 4; ++i) {
                const int s = qq * 4 + i;
                const float bv = (i == 0) ? bm.x : (i == 1) ? bm.y : (i == 2) ? bm.z : bm.w;
                const float dA = __expf(dtv * a[s]);
                P[s] *= dA;
                h[s] = fmaf(dA, h[s], dx * bv);
            }
        }
        dtv = dtv_n; xcv = xcv_n;
    }
    const size_t o0 = (((size_t)b * NCH_ + j) * DS_) * DI_ + d;
    #pragma unroll
    for (int s = 0; s < DS_; ++s) {
        Pc[o0 + (size_t)s * DI_] = P[s];
        Hc[o0 + (size_t)s * DI_] = h[s];
    }
}

__global__ __launch_bounds__(256) void scan_combine(
    const float* __restrict__ Pc, float* __restrict__ Hc)
{
    const size_t idx = (size_t)blockIdx.x * 256 + threadIdx.x;   // over BN*DS*DI
    const size_t b   = idx / (DS_ * DI_);
    const size_t rem = idx % (DS_ * DI_);
    const size_t base   = b * ((size_t)NCH_ * DS_ * DI_) + rem;
    const size_t stride = (size_t)DS_ * DI_;
    float h = 0.f;
    #pragma unroll
    for (int j = 0; j < NCH_; ++j) {
        const size_t o = base + (size_t)j * stride;
        const float P  = Pc[o];
        const float hl = Hc[o];
        Hc[o] = h;                 // incoming state for chunk j
        h = fmaf(P, h, hl);
    }
}

__global__ __launch_bounds__(256) void scan_part2(
    const unsigned short* __restrict__ dt, const unsigned short* __restrict__ xcb,
    const unsigned short* __restrict__ gate,     // bf16
    const float* __restrict__ Bm, const float* __restrict__ Cm,
    const float* __restrict__ A, const float* __restrict__ Dp,
    const float* __restrict__ Hin, unsigned short* __restrict__ ygb)
{
    const int tid = threadIdx.x;
    const int d   = blockIdx.x * 256 + tid;
    const int b   = blockIdx.y;
    const int j   = blockIdx.z;
    const int t0  = j * TL_;

    __shared__ float s_Bm[TL_ * DS_];
    __shared__ float s_Cm[TL_ * DS_];
    {
        const float* bsrc = Bm + ((size_t)b * L_ + t0) * DS_;
        const float* csrc = Cm + ((size_t)b * L_ + t0) * DS_;
        s_Bm[tid]       = bsrc[tid];
        s_Bm[256 + tid] = bsrc[256 + tid];
        s_Cm[tid]       = csrc[tid];
        s_Cm[256 + tid] = csrc[256 + tid];
    }
    float a[DS_];
    #pragma unroll
    for (int qq = 0; qq < 4; ++qq)
        *(float4*)&a[qq * 4] = *(const float4*)(A + (size_t)d * DS_ + qq * 4);
    const float dp = Dp[d];

    float h[DS_];
    {
        const size_t o0 = (((size_t)b * NCH_ + j) * DS_) * DI_ + d;
        #pragma unroll
        for (int s = 0; s < DS_; ++s) h[s] = Hin[o0 + (size_t)s * DI_];
    }
    __syncthreads();

    const size_t rbase = ((size_t)b * L_ + t0) * DI_ + d;
    const unsigned short* dtp = dt   + rbase;
    const unsigned short* xcp = xcb  + rbase;
    const unsigned short* gvp = gate + rbase;
    unsigned short* yp = ygb + rbase;

    float dtv = b2f(dtp[0]), xcv = b2f(xcp[0]), gv = b2f(gvp[0]);
    #pragma unroll 4
    for (int t = 0; t < TL_; ++t) {
        float dtv_n = 0.f, xcv_n = 0.f, gv_n = 0.f;
        if (t + 1 < TL_) {
            dtv_n = b2f(dtp[(size_t)(t + 1) * DI_]);
            xcv_n = b2f(xcp[(size_t)(t + 1) * DI_]);
            gv_n  = b2f(gvp[(size_t)(t + 1) * DI_]);
        }
        const float dx = dtv * xcv;
        float y0 = 0.f, y1 = 0.f, y2 = 0.f, y3 = 0.f;
        #pragma unroll
        for (int qq = 0; qq < 4; ++qq) {
            const float4 bm = *(const float4*)&s_Bm[t * DS_ + qq * 4];
            const float4 cm = *(const float4*)&s_Cm[t * DS_ + qq * 4];
            #pragma unroll
            for (int i = 0; i < 4; ++i) {
                const int s = qq * 4 + i;
                const float bv = (i == 0) ? bm.x : (i == 1) ? bm.y : (i == 2) ? bm.z : bm.w;
                const float cv = (i == 0) ? cm.x : (i == 1) ? cm.y : (i == 2) ? cm.z : cm.w;
                const float dA = __expf(dtv * a[s]);
                h[s] = fmaf(dA, h[s], dx * bv);
                if (i == 0) y0 = fmaf(h[s], cv, y0);
                else if (i == 1) y1 = fmaf(h[s], cv, y1);
                else if (i == 2) y2 = fmaf(h[s], cv, y2);
                else y3 = fmaf(h[s], cv, y3);
            }
        }
        float y = (y0 + y1) + (y2 + y3);
        y = fmaf(xcv, dp, y);
        const float r = y * (gv / (1.0f + __expf(-gv)));
        yp[(size_t)t * DI_] = f2b(r);
        dtv = dtv_n; xcv = xcv_n; gv = gv_n;
    }
}

// ---------------------------------------------------------------------------
extern "C" void kernel_launch(void* const* d_in, const int* in_sizes, int n_in,
                              void* d_out, int out_size, void* d_ws, size_t ws_size,
                              hipStream_t stream)
{
    const float* x      = (const float*)d_in[0];
    const float* in_w   = (const float*)d_in[1];
    const float* in_b   = (const float*)d_in[2];
    const float* conv_w = (const float*)d_in[3];
    const float* conv_b = (const float*)d_in[4];
    const float* A      = (const float*)d_in[5];
    const float* Dp     = (const float*)d_in[6];
    const float* B_w    = (const float*)d_in[7];
    const float* B_b    = (const float*)d_in[8];
    const float* C_w    = (const float*)d_in[9];
    const float* C_b    = (const float*)d_in[10];
    const float* dt_w   = (const float*)d_in[11];
    const float* dt_b   = (const float*)d_in[12];
    const float* out_w  = (const float*)d_in[13];
    const float* out_b  = (const float*)d_in[14];
    float* out = (float*)d_out;

    // ---- workspace layout (aliased) ----
    unsigned short* dtb = (unsigned short*)d_ws;   // [M][DI] bf16, 8MB
    float* Bm   = (float*)(dtb + (size_t)M_ * DI_);          // [M][16] 128KB
    float* Cm   = Bm  + (size_t)M_ * DS_;                    // [M][16] 128KB
    unsigned short* w3  = (unsigned short*)(Cm + (size_t)M_ * DS_); // out_w^T  4MB
    unsigned short* w1  = w3  + (size_t)DM_ * DI_;                  // in_w^T   8MB
    unsigned short* xb  = w1  + (size_t)2 * DI_ * DM_;              // x bf16   4MB
    unsigned short* w2  = xb  + (size_t)M_ * DM_;                   // dtBC^T   8.5MB
    unsigned short* xcb = w2  + (size_t)NBC_ * DI_;                 // xc bf16  8MB
    unsigned short* xzb = xcb + (size_t)M_ * DI_;                   // xz bf16  8MB
    unsigned short* gtb = xzb + (size_t)M_ * DI_;                   // gate bf16 8MB
    unsigned short* ygb = xcb;                     // alias: p2 reads/writes same offsets
    float* Pc = (float*)w1;                        // 8MB over w1 (dead after in_proj)
    float* Hc = (float*)xb;                        // 8MB over xb + w2 head (dead after dtBC GEMM)

    // 1) fused prep: xb, w1, w2 (incl. bc rows), w3 in ONE dispatch
    prep<<<12544, 256, 0, stream>>>(x, in_w, dt_w, out_w, B_w, C_w, xb, w1, w2, w3);

    // 2) [xzb | gtb] = bf16(x @ in_w + in_b)   (M=2048, N=4096, K=1024)
    gemm_mfma<64, 128, 0><<<dim3(2 * DI_ / 128, M_ / 64), 256, 0, stream>>>(
        xb, w1, in_b, nullptr, nullptr,
        nullptr, nullptr, nullptr, xzb, gtb, M_, 2 * DI_, DM_, DI_);

    // 3) depthwise conv + silu (bf16 xcb)
    conv_silu<<<(BN_ * L_ * DI_) / 256, 256, 0, stream>>>(xzb, conv_w, conv_b, xcb);

    // 4) dtb(bf16) = softplus(xc @ dt_w + dt_b); Bm,Cm fp32
    gemm_mfma<64, 128, 1><<<dim3(NBC_ / 128, M_ / 64), 256, 0, stream>>>(
        xcb, w2, dt_b, B_b, C_b,
        nullptr, Bm, Cm, dtb, nullptr, M_, NBC_, DI_, NBC_);

    // 5) chunked scan: part1 -> combine -> part2 (writes bf16 ygb)
    scan_part1<<<dim3(DI_ / 256, BN_, NCH_), 256, 0, stream>>>(
        dtb, xcb, Bm, A, Pc, Hc);
    scan_combine<<<(BN_ * DI_ * DS_) / 256, 256, 0, stream>>>(Pc, Hc);
    scan_part2<<<dim3(DI_ / 256, BN_, NCH_), 256, 0, stream>>>(
        dtb, xcb, gtb, Bm, Cm, A, Dp, Hc, ygb);

    // 6) out = yg @ out_w + out_b   (M=2048, N=1024, K=2048)
    gemm_mfma<64, 64, 2><<<dim3(DM_ / 64, M_ / 64), 256, 0, stream>>>(
        ygb, w3, out_b, nullptr, nullptr,
        out, nullptr, nullptr, nullptr, nullptr, M_, DM_, DI_, DM_);
}

// Round 12
// 169.249 us; speedup vs baseline: 1.3053x; 1.0802x over previous
//
#include <hip/hip_runtime.h>
#include <hip/hip_bf16.h>
#include <math.h>

// Problem constants: BN=2, L=1024, DM=1024, D_STATE=16, D_CONV=4, EXPAND=2,
// D_INNER=2048. M = BN*L = 2048.
#define BN_   2
#define L_    1024
#define DM_   1024
#define DS_   16
#define DI_   2048
#define M_    (BN_ * L_)
#define NBC_  2176           // dt(2048) + Bm(16) + Cm(16) + pad(96), 17*128

typedef __attribute__((ext_vector_type(8))) short short8;
typedef __attribute__((ext_vector_type(4))) float f32x4;

__device__ __forceinline__ unsigned short f2b(float f) {
    union { float f; unsigned u; } x; x.f = f;
    unsigned r = x.u + 0x7fffu + ((x.u >> 16) & 1u);   // RNE
    return (unsigned short)(r >> 16);
}
__device__ __forceinline__ float b2f(unsigned short u) {
    union { unsigned u; float f; } x; x.u = ((unsigned)u) << 16; return x.f;
}

__device__ __forceinline__ void gload_lds16(const unsigned short* g, unsigned short* l) {
    __builtin_amdgcn_global_load_lds(
        (const __attribute__((address_space(1))) void*)g,
        (__attribute__((address_space(3))) void*)l, 16, 0, 0);
}

// ---------------------------------------------------------------------------
// Fused prep: one dispatch does x->bf16 cast, in_w/dt_w/out_w transpose-cast,
// and B_w/C_w pack. Sections by blockIdx.x (uniform per block -> barriers ok).
// ---------------------------------------------------------------------------
__device__ __forceinline__ void tr_tile(
    const float* __restrict__ in, unsigned short* __restrict__ out,
    int R, int C, int bx, int by)
{
    __shared__ float t[32][33];
    const int tx = threadIdx.x & 31;
    const int ty = (threadIdx.x >> 5) * 4;
    #pragma unroll
    for (int j = 0; j < 4; ++j)
        t[ty + j][tx] = in[(size_t)(by + ty + j) * C + bx + tx];
    __syncthreads();
    #pragma unroll
    for (int j = 0; j < 4; ++j)
        out[(size_t)(bx + ty + j) * R + by + tx] = f2b(t[tx][ty + j]);
}

__global__ __launch_bounds__(256) void prep(
    const float* __restrict__ x,
    const float* __restrict__ in_w, const float* __restrict__ dt_w,
    const float* __restrict__ out_w,
    const float* __restrict__ Bw, const float* __restrict__ Cw,
    unsigned short* __restrict__ xb, unsigned short* __restrict__ w1,
    unsigned short* __restrict__ w2, unsigned short* __restrict__ w3)
{
    const int blk = blockIdx.x;
    const int tid = threadIdx.x;
    if (blk < 2048) {                                   // cast x
        const int i = (blk * 256 + tid) * 4;
        if (i < M_ * DM_) {
            float4 v = *(const float4*)(x + i);
            ushort4 o; o.x = f2b(v.x); o.y = f2b(v.y); o.z = f2b(v.z); o.w = f2b(v.w);
            *(ushort4*)(xb + i) = o;
        }
    } else if (blk < 6144) {                            // in_w^T
        const int id = blk - 2048;
        tr_tile(in_w, w1, DM_, 2 * DI_, (id & 127) * 32, (id >> 7) * 32);
    } else if (blk < 10240) {                           // dt_w^T
        const int id = blk - 6144;
        tr_tile(dt_w, w2, DI_, DI_, (id & 63) * 32, (id >> 6) * 32);
    } else if (blk < 12288) {                           // out_w^T
        const int id = blk - 10240;
        tr_tile(out_w, w3, DI_, DM_, (id & 31) * 32, (id >> 5) * 32);
    } else {                                            // bc_pack
        const int idx = (blk - 12288) * 256 + tid;      // 32*2048
        const int r = idx >> 11;
        const int k = idx & 2047;
        const float* src = (r < 16) ? Bw : Cw;
        w2[(size_t)(2048 + r) * 2048 + k] = f2b(src[k * 16 + (r & 15)]);
    }
}

// ---------------------------------------------------------------------------
// bf16 MFMA GEMM, 2-stage double-buffered (proven R8/R11 schedule), now with
// 8 WAVES / 512 THREADS per block: same tile, same LDS (48/32KB -> still
// 3 blocks/CU), but 24 waves/CU instead of 12 -> 2x the in-flight load
// concurrency (T x waves/CU ~ const across R7/R8/R10 => latency-concurrency
// bound, Little's law). Wave (2x4) owns a (BM/2)x(BN/4) sub-tile.
// Read-side XOR swizzle (bank-conflict-free) + XCD-aware bijective block
// swizzle retained. BK=64, 16x16x32 frags.
//   MODE 0: bf16 output, column-split at NS -> U0 | U1        (in_proj)
//   MODE 1: c<2048 softplus -> bf16 U0; 2048..2063 -> F1(+b1) fp32;
//           2064..2079 -> F2(+b2) fp32; pad discarded          (dt+B+C)
//   MODE 2: fp32 single output F0                              (out_proj)
// ---------------------------------------------------------------------------
template<int BM, int BN, int MODE>
__global__ __launch_bounds__(512) void gemm_mfma(
    const unsigned short* __restrict__ A,   // [M][K] bf16
    const unsigned short* __restrict__ Bt,  // [N][K] bf16
    const float* __restrict__ b0, const float* __restrict__ b1,
    const float* __restrict__ b2,
    float* __restrict__ F0, float* __restrict__ F1, float* __restrict__ F2,
    unsigned short* __restrict__ U0, unsigned short* __restrict__ U1,
    int M, int N, int K, int NS)
{
    constexpr int MF  = BM / 32;   // m-frags per wave (wave covers BM/2 rows)
    constexpr int NF  = BN / 64;   // n-frags per wave (wave covers BN/4 cols)
    constexpr int ACW = BM / 64;   // A 8-row chunks staged per wave (8 waves)
    constexpr int BCW = BN / 64;   // B 8-row chunks staged per wave

    __shared__ unsigned short Asl[2][BM * 64];
    __shared__ unsigned short Bsl[2][BN * 64];

    const int tid  = threadIdx.x;
    const int wave = tid >> 6;     // 0..7
    const int lane = tid & 63;

    // XCD-aware bijective swizzle (all call sites have nwg % 8 == 0).
    const int gx  = gridDim.x, gy = gridDim.y;
    const int bid = blockIdx.y * gx + blockIdx.x;
    const int q   = (gx * gy) >> 3;
    const int nb  = (bid & 7) * q + (bid >> 3);
    const int by  = nb % gy;
    const int bx  = nb / gy;

    const int row0 = by * BM;
    const int col0 = bx * BN;
    const int wr   = (wave >> 2) * (BM / 2);   // wave-row: 2 rows of waves
    const int wc   = (wave & 3) * (BN / 4);    // wave-col: 4 cols of waves

    const int srow = lane >> 3;                          // row within 8-row chunk
    const int scol = ((lane & 7) ^ (lane >> 3)) * 8;     // pre-swizzled source col

    auto stage = [&](int buf, int kt) {
        #pragma unroll
        for (int i = 0; i < ACW; ++i) {
            const int ch = wave * ACW + i;               // 8 waves x ACW = BM/8
            gload_lds16(A + (size_t)(row0 + ch * 8 + srow) * K + kt + scol,
                        &Asl[buf][ch * 512]);
        }
        #pragma unroll
        for (int i = 0; i < BCW; ++i) {
            const int ch = wave * BCW + i;               // 8 waves x BCW = BN/8
            gload_lds16(Bt + (size_t)(col0 + ch * 8 + srow) * K + kt + scol,
                        &Bsl[buf][ch * 512]);
        }
    };

    f32x4 acc[MF][NF];
    #pragma unroll
    for (int m = 0; m < MF; ++m)
        #pragma unroll
        for (int n = 0; n < NF; ++n)
            acc[m][n] = (f32x4){0.f, 0.f, 0.f, 0.f};

    stage(0, 0);
    __syncthreads();

    const int nk = K >> 6;
    int cur = 0;
    for (int kt = 0; kt < nk; ++kt) {
        if (kt + 1 < nk) stage(cur ^ 1, (kt + 1) << 6);

        short8 af[MF][2], bf[NF][2];
        const int lrow  = lane & 15;
        const int xsw   = (lane & 7) * 8;                // read-side XOR
        const int cbase = (lane >> 4) * 8;
        #pragma unroll
        for (int m = 0; m < MF; ++m)
            #pragma unroll
            for (int kk = 0; kk < 2; ++kk)
                af[m][kk] = *(const short8*)
                    &Asl[cur][(wr + m * 16 + lrow) * 64 + ((kk * 32 + cbase) ^ xsw)];
        #pragma unroll
        for (int n = 0; n < NF; ++n)
            #pragma unroll
            for (int kk = 0; kk < 2; ++kk)
                bf[n][kk] = *(const short8*)
                    &Bsl[cur][(wc + n * 16 + lrow) * 64 + ((kk * 32 + cbase) ^ xsw)];

        #pragma unroll
        for (int m = 0; m < MF; ++m)
            #pragma unroll
            for (int n = 0; n < NF; ++n) {
                acc[m][n] = __builtin_amdgcn_mfma_f32_16x16x32_bf16(
                    af[m][0], bf[n][0], acc[m][n], 0, 0, 0);
                acc[m][n] = __builtin_amdgcn_mfma_f32_16x16x32_bf16(
                    af[m][1], bf[n][1], acc[m][n], 0, 0, 0);
            }
        __syncthreads();   // drains prefetch vmcnt + protects cur from overwrite
        cur ^= 1;
    }

    // epilogue: C/D layout col=lane&15, row=(lane>>4)*4+j
    const int crow = (lane >> 4) * 4;
    const int ccol = lane & 15;
    #pragma unroll
    for (int m = 0; m < MF; ++m)
        #pragma unroll
        for (int n = 0; n < NF; ++n) {
            const int c = col0 + wc + n * 16 + ccol;
            if (MODE == 0) {
                const float bv = b0[c];
                unsigned short* dst = (c < NS) ? (U0 + c) : (U1 + (c - NS));
                #pragma unroll
                for (int j = 0; j < 4; ++j) {
                    const int r = row0 + wr + m * 16 + crow + j;
                    dst[(size_t)r * NS] = f2b(acc[m][n][j] + bv);
                }
            } else if (MODE == 1) {
                if (c < 2048) {
                    const float bv = b0[c];
                    #pragma unroll
                    for (int j = 0; j < 4; ++j) {
                        const int r = row0 + wr + m * 16 + crow + j;
                        float v = acc[m][n][j] + bv;
                        v = (v > 20.0f) ? v : log1pf(__expf(v));
                        U0[(size_t)r * 2048 + c] = f2b(v);
                    }
                } else if (c < 2064) {
                    const float bv = b1[c - 2048];
                    #pragma unroll
                    for (int j = 0; j < 4; ++j) {
                        const int r = row0 + wr + m * 16 + crow + j;
                        F1[(size_t)r * 16 + (c - 2048)] = acc[m][n][j] + bv;
                    }
                } else if (c < 2080) {
                    const float bv = b2[c - 2064];
                    #pragma unroll
                    for (int j = 0; j < 4; ++j) {
                        const int r = row0 + wr + m * 16 + crow + j;
                        F2[(size_t)r * 16 + (c - 2064)] = acc[m][n][j] + bv;
                    }
                }   // pad columns: discard
            } else {
                const float bv = b0[c];
                #pragma unroll
                for (int j = 0; j < 4; ++j) {
                    const int r = row0 + wr + m * 16 + crow + j;
                    F0[(size_t)r * NS + c] = acc[m][n][j] + bv;
                }
            }
        }
}

// ---------------------------------------------------------------------------
// Depthwise conv (window 4, SAME: taps t-1..t+2) + bias + SiLU.
// Reads bf16 xzb [M][DI]; writes bf16 xcb only.
// ---------------------------------------------------------------------------
__global__ __launch_bounds__(256) void conv_silu(
    const unsigned short* __restrict__ xzb, const float* __restrict__ cw,
    const float* __restrict__ cb, unsigned short* __restrict__ xcb)
{
    const int idx = blockIdx.x * 256 + threadIdx.x;
    if (idx >= BN_ * L_ * DI_) return;
    const int d = idx & (DI_ - 1);
    const int t = (idx / DI_) & (L_ - 1);
    const int b = idx / (DI_ * L_);

    float acc = cb[d];
    #pragma unroll
    for (int w = 0; w < 4; ++w) {
        const int tt = t + w - 1;
        if (tt >= 0 && tt < L_)
            acc = fmaf(b2f(xzb[((size_t)(b * L_ + tt)) * DI_ + d]), cw[w * DI_ + d], acc);
    }
    const float s = acc / (1.0f + __expf(-acc));
    xcb[idx] = f2b(s);
}

// ---------------------------------------------------------------------------
// Chunked selective scan, one CHANNEL per lane, 16 states in registers.
// dt consumed as bf16.
// ---------------------------------------------------------------------------
#define NCH_ 32
#define TL_  (L_ / NCH_)   // 32

__global__ __launch_bounds__(256) void scan_part1(
    const unsigned short* __restrict__ dt, const unsigned short* __restrict__ xcb,
    const float* __restrict__ Bm, const float* __restrict__ A,
    float* __restrict__ Pc, float* __restrict__ Hc)
{
    const int tid = threadIdx.x;
    const int d   = blockIdx.x * 256 + tid;
    const int b   = blockIdx.y;
    const int j   = blockIdx.z;
    const int t0  = j * TL_;

    __shared__ float s_Bm[TL_ * DS_];                  // 2 KB
    {
        const float* src = Bm + ((size_t)b * L_ + t0) * DS_;
        s_Bm[tid]       = src[tid];
        s_Bm[256 + tid] = src[256 + tid];
    }
    float a[DS_];
    #pragma unroll
    for (int qq = 0; qq < 4; ++qq)
        *(float4*)&a[qq * 4] = *(const float4*)(A + (size_t)d * DS_ + qq * 4);
    __syncthreads();

    const unsigned short* dtp = dt + ((size_t)b * L_ + t0) * DI_ + d;
    const unsigned short* xcp = xcb + ((size_t)b * L_ + t0) * DI_ + d;

    float h[DS_] = {};
    float P[DS_];
    #pragma unroll
    for (int s = 0; s < DS_; ++s) P[s] = 1.0f;

    float dtv = b2f(dtp[0]), xcv = b2f(xcp[0]);
    #pragma unroll 4
    for (int t = 0; t < TL_; ++t) {
        float dtv_n = 0.f, xcv_n = 0.f;
        if (t + 1 < TL_) {
            dtv_n = b2f(dtp[(size_t)(t + 1) * DI_]);
            xcv_n = b2f(xcp[(size_t)(t + 1) * DI_]);
        }
        const float dx = dtv * xcv;
        #pragma unroll
        for (int qq = 0; qq < 4; ++qq) {
            const float4 bm = *(const float4*)&s_Bm[t * DS_ + qq * 4];
            #pragma unroll
            for (int i = 0; i < 4; ++i) {
                const int s = qq * 4 + i;
                const float bv = (i == 0) ? bm.x : (i == 1) ? bm.y : (i == 2) ? bm.z : bm.w;
                const float dA = __expf(dtv * a[s]);
                P[s] *= dA;
                h[s] = fmaf(dA, h[s], dx * bv);
            }
        }
        dtv = dtv_n; xcv = xcv_n;
    }
    const size_t o0 = (((size_t)b * NCH_ + j) * DS_) * DI_ + d;
    #pragma unroll
    for (int s = 0; s < DS_; ++s) {
        Pc[o0 + (size_t)s * DI_] = P[s];
        Hc[o0 + (size_t)s * DI_] = h[s];
    }
}

__global__ __launch_bounds__(256) void scan_combine(
    const float* __restrict__ Pc, float* __restrict__ Hc)
{
    const size_t idx = (size_t)blockIdx.x * 256 + threadIdx.x;   // over BN*DS*DI
    const size_t b   = idx / (DS_ * DI_);
    const size_t rem = idx % (DS_ * DI_);
    const size_t base   = b * ((size_t)NCH_ * DS_ * DI_) + rem;
    const size_t stride = (size_t)DS_ * DI_;
    float h = 0.f;
    #pragma unroll
    for (int j = 0; j < NCH_; ++j) {
        const size_t o = base + (size_t)j * stride;
        const float P  = Pc[o];
        const float hl = Hc[o];
        Hc[o] = h;                 // incoming state for chunk j
        h = fmaf(P, h, hl);
    }
}

__global__ __launch_bounds__(256) void scan_part2(
    const unsigned short* __restrict__ dt, const unsigned short* __restrict__ xcb,
    const unsigned short* __restrict__ gate,     // bf16
    const float* __restrict__ Bm, const float* __restrict__ Cm,
    const float* __restrict__ A, const float* __restrict__ Dp,
    const float* __restrict__ Hin, unsigned short* __restrict__ ygb)
{
    const int tid = threadIdx.x;
    const int d   = blockIdx.x * 256 + tid;
    const int b   = blockIdx.y;
    const int j   = blockIdx.z;
    const int t0  = j * TL_;

    __shared__ float s_Bm[TL_ * DS_];
    __shared__ float s_Cm[TL_ * DS_];
    {
        const float* bsrc = Bm + ((size_t)b * L_ + t0) * DS_;
        const float* csrc = Cm + ((size_t)b * L_ + t0) * DS_;
        s_Bm[tid]       = bsrc[tid];
        s_Bm[256 + tid] = bsrc[256 + tid];
        s_Cm[tid]       = csrc[tid];
        s_Cm[256 + tid] = csrc[256 + tid];
    }
    float a[DS_];
    #pragma unroll
    for (int qq = 0; qq < 4; ++qq)
        *(float4*)&a[qq * 4] = *(const float4*)(A + (size_t)d * DS_ + qq * 4);
    const float dp = Dp[d];

    float h[DS_];
    {
        const size_t o0 = (((size_t)b * NCH_ + j) * DS_) * DI_ + d;
        #pragma unroll
        for (int s = 0; s < DS_; ++s) h[s] = Hin[o0 + (size_t)s * DI_];
    }
    __syncthreads();

    const size_t rbase = ((size_t)b * L_ + t0) * DI_ + d;
    const unsigned short* dtp = dt   + rbase;
    const unsigned short* xcp = xcb  + rbase;
    const unsigned short* gvp = gate + rbase;
    unsigned short* yp = ygb + rbase;

    float dtv = b2f(dtp[0]), xcv = b2f(xcp[0]), gv = b2f(gvp[0]);
    #pragma unroll 4
    for (int t = 0; t < TL_; ++t) {
        float dtv_n = 0.f, xcv_n = 0.f, gv_n = 0.f;
        if (t + 1 < TL_) {
            dtv_n = b2f(dtp[(size_t)(t + 1) * DI_]);
            xcv_n = b2f(xcp[(size_t)(t + 1) * DI_]);
            gv_n  = b2f(gvp[(size_t)(t + 1) * DI_]);
        }
        const float dx = dtv * xcv;
        float y0 = 0.f, y1 = 0.f, y2 = 0.f, y3 = 0.f;
        #pragma unroll
        for (int qq = 0; qq < 4; ++qq) {
            const float4 bm = *(const float4*)&s_Bm[t * DS_ + qq * 4];
            const float4 cm = *(const float4*)&s_Cm[t * DS_ + qq * 4];
            #pragma unroll
            for (int i = 0; i < 4; ++i) {
                const int s = qq * 4 + i;
                const float bv = (i == 0) ? bm.x : (i == 1) ? bm.y : (i == 2) ? bm.z : bm.w;
                const float cv = (i == 0) ? cm.x : (i == 1) ? cm.y : (i == 2) ? cm.z : cm.w;
                const float dA = __expf(dtv * a[s]);
                h[s] = fmaf(dA, h[s], dx * bv);
                if (i == 0) y0 = fmaf(h[s], cv, y0);
                else if (i == 1) y1 = fmaf(h[s], cv, y1);
                else if (i == 2) y2 = fmaf(h[s], cv, y2);
                else y3 = fmaf(h[s], cv, y3);
            }
        }
        float y = (y0 + y1) + (y2 + y3);
        y = fmaf(xcv, dp, y);
        const float r = y * (gv / (1.0f + __expf(-gv)));
        yp[(size_t)t * DI_] = f2b(r);
        dtv = dtv_n; xcv = xcv_n; gv = gv_n;
    }
}

// ---------------------------------------------------------------------------
extern "C" void kernel_launch(void* const* d_in, const int* in_sizes, int n_in,
                              void* d_out, int out_size, void* d_ws, size_t ws_size,
                              hipStream_t stream)
{
    const float* x      = (const float*)d_in[0];
    const float* in_w   = (const float*)d_in[1];
    const float* in_b   = (const float*)d_in[2];
    const float* conv_w = (const float*)d_in[3];
    const float* conv_b = (const float*)d_in[4];
    const float* A      = (const float*)d_in[5];
    const float* Dp     = (const float*)d_in[6];
    const float* B_w    = (const float*)d_in[7];
    const float* B_b    = (const float*)d_in[8];
    const float* C_w    = (const float*)d_in[9];
    const float* C_b    = (const float*)d_in[10];
    const float* dt_w   = (const float*)d_in[11];
    const float* dt_b   = (const float*)d_in[12];
    const float* out_w  = (const float*)d_in[13];
    const float* out_b  = (const float*)d_in[14];
    float* out = (float*)d_out;

    // ---- workspace layout (aliased) ----
    unsigned short* dtb = (unsigned short*)d_ws;   // [M][DI] bf16, 8MB
    float* Bm   = (float*)(dtb + (size_t)M_ * DI_);          // [M][16] 128KB
    float* Cm   = Bm  + (size_t)M_ * DS_;                    // [M][16] 128KB
    unsigned short* w3  = (unsigned short*)(Cm + (size_t)M_ * DS_); // out_w^T  4MB
    unsigned short* w1  = w3  + (size_t)DM_ * DI_;                  // in_w^T   8MB
    unsigned short* xb  = w1  + (size_t)2 * DI_ * DM_;              // x bf16   4MB
    unsigned short* w2  = xb  + (size_t)M_ * DM_;                   // dtBC^T   8.5MB
    unsigned short* xcb = w2  + (size_t)NBC_ * DI_;                 // xc bf16  8MB
    unsigned short* xzb = xcb + (size_t)M_ * DI_;                   // xz bf16  8MB
    unsigned short* gtb = xzb + (size_t)M_ * DI_;                   // gate bf16 8MB
    unsigned short* ygb = xcb;                     // alias: p2 reads/writes same offsets
    float* Pc = (float*)w1;                        // 8MB over w1 (dead after in_proj)
    float* Hc = (float*)xb;                        // 8MB over xb + w2 head (dead after dtBC GEMM)

    // 1) fused prep: xb, w1, w2 (incl. bc rows), w3 in ONE dispatch
    prep<<<12544, 256, 0, stream>>>(x, in_w, dt_w, out_w, B_w, C_w, xb, w1, w2, w3);

    // 2) [xzb | gtb] = bf16(x @ in_w + in_b)   (M=2048, N=4096, K=1024)
    gemm_mfma<64, 128, 0><<<dim3(2 * DI_ / 128, M_ / 64), 512, 0, stream>>>(
        xb, w1, in_b, nullptr, nullptr,
        nullptr, nullptr, nullptr, xzb, gtb, M_, 2 * DI_, DM_, DI_);

    // 3) depthwise conv + silu (bf16 xcb)
    conv_silu<<<(BN_ * L_ * DI_) / 256, 256, 0, stream>>>(xzb, conv_w, conv_b, xcb);

    // 4) dtb(bf16) = softplus(xc @ dt_w + dt_b); Bm,Cm fp32
    gemm_mfma<64, 128, 1><<<dim3(NBC_ / 128, M_ / 64), 512, 0, stream>>>(
        xcb, w2, dt_b, B_b, C_b,
        nullptr, Bm, Cm, dtb, nullptr, M_, NBC_, DI_, NBC_);

    // 5) chunked scan: part1 -> combine -> part2 (writes bf16 ygb)
    scan_part1<<<dim3(DI_ / 256, BN_, NCH_), 256, 0, stream>>>(
        dtb, xcb, Bm, A, Pc, Hc);
    scan_combine<<<(BN_ * DI_ * DS_) / 256, 256, 0, stream>>>(Pc, Hc);
    scan_part2<<<dim3(DI_ / 256, BN_, NCH_), 256, 0, stream>>>(
        dtb, xcb, gtb, Bm, Cm, A, Dp, Hc, ygb);

    // 6) out = yg @ out_w + out_b   (M=2048, N=1024, K=2048)
    gemm_mfma<64, 64, 2><<<dim3(DM_ / 64, M_ / 64), 512, 0, stream>>>(
        ygb, w3, out_b, nullptr, nullptr,
        out, nullptr, nullptr, nullptr, nullptr, M_, DM_, DI_, DM_);
}

// Round 13
// 165.336 us; speedup vs baseline: 1.3362x; 1.0237x over previous
//
#include <hip/hip_runtime.h>
#include <hip/hip_bf16.h>
#include <math.h>

// Problem constants: BN=2, L=1024, DM=1024, D_STATE=16, D_CONV=4, EXPAND=2,
// D_INNER=2048. M = BN*L = 2048.
#define BN_   2
#define L_    1024
#define DM_   1024
#define DS_   16
#define DI_   2048
#define M_    (BN_ * L_)
#define NBC_  2176           // dt(2048) + Bm(16) + Cm(16) + pad(96), 17*128

typedef __attribute__((ext_vector_type(8))) short short8;
typedef __attribute__((ext_vector_type(4))) float f32x4;

__device__ __forceinline__ unsigned short f2b(float f) {
    union { float f; unsigned u; } x; x.f = f;
    unsigned r = x.u + 0x7fffu + ((x.u >> 16) & 1u);   // RNE
    return (unsigned short)(r >> 16);
}
__device__ __forceinline__ float b2f(unsigned short u) {
    union { unsigned u; float f; } x; x.u = ((unsigned)u) << 16; return x.f;
}

__device__ __forceinline__ void gload_lds16(const unsigned short* g, unsigned short* l) {
    __builtin_amdgcn_global_load_lds(
        (const __attribute__((address_space(1))) void*)g,
        (__attribute__((address_space(3))) void*)l, 16, 0, 0);
}

// ---------------------------------------------------------------------------
// Fused prep: one dispatch does x->bf16 cast, in_w/dt_w/out_w transpose-cast,
// and B_w/C_w pack. Sections by blockIdx.x (uniform per block -> barriers ok).
// ---------------------------------------------------------------------------
__device__ __forceinline__ void tr_tile(
    const float* __restrict__ in, unsigned short* __restrict__ out,
    int R, int C, int bx, int by)
{
    __shared__ float t[32][33];
    const int tx = threadIdx.x & 31;
    const int ty = (threadIdx.x >> 5) * 4;
    #pragma unroll
    for (int j = 0; j < 4; ++j)
        t[ty + j][tx] = in[(size_t)(by + ty + j) * C + bx + tx];
    __syncthreads();
    #pragma unroll
    for (int j = 0; j < 4; ++j)
        out[(size_t)(bx + ty + j) * R + by + tx] = f2b(t[tx][ty + j]);
}

__global__ __launch_bounds__(256) void prep(
    const float* __restrict__ x,
    const float* __restrict__ in_w, const float* __restrict__ dt_w,
    const float* __restrict__ out_w,
    const float* __restrict__ Bw, const float* __restrict__ Cw,
    unsigned short* __restrict__ xb, unsigned short* __restrict__ w1,
    unsigned short* __restrict__ w2, unsigned short* __restrict__ w3)
{
    const int blk = blockIdx.x;
    const int tid = threadIdx.x;
    if (blk < 2048) {                                   // cast x
        const int i = (blk * 256 + tid) * 4;
        if (i < M_ * DM_) {
            float4 v = *(const float4*)(x + i);
            ushort4 o; o.x = f2b(v.x); o.y = f2b(v.y); o.z = f2b(v.z); o.w = f2b(v.w);
            *(ushort4*)(xb + i) = o;
        }
    } else if (blk < 6144) {                            // in_w^T
        const int id = blk - 2048;
        tr_tile(in_w, w1, DM_, 2 * DI_, (id & 127) * 32, (id >> 7) * 32);
    } else if (blk < 10240) {                           // dt_w^T
        const int id = blk - 6144;
        tr_tile(dt_w, w2, DI_, DI_, (id & 63) * 32, (id >> 6) * 32);
    } else if (blk < 12288) {                           // out_w^T
        const int id = blk - 10240;
        tr_tile(out_w, w3, DI_, DM_, (id & 31) * 32, (id >> 5) * 32);
    } else {                                            // bc_pack
        const int idx = (blk - 12288) * 256 + tid;      // 32*2048
        const int r = idx >> 11;
        const int k = idx & 2047;
        const float* src = (r < 16) ? Bw : Cw;
        w2[(size_t)(2048 + r) * 2048 + k] = f2b(src[k * 16 + (r & 15)]);
    }
}

// ---------------------------------------------------------------------------
// bf16 MFMA GEMM, 2-stage double-buffered, 8 waves / 512 threads (R12 —
// proven best: 24 waves/CU for 64x128, latency-concurrency regime).
// Read-side XOR swizzle (bank-conflict-free) + XCD-aware bijective block
// swizzle. BK=64, 16x16x32 frags. Wave (2x4) owns (BM/2)x(BN/4).
//   MODE 0: bf16 output, column-split at NS -> U0 | U1        (in_proj)
//   MODE 1: c<2048 softplus -> bf16 U0; 2048..2063 -> F1(+b1) fp32;
//           2064..2079 -> F2(+b2) fp32; pad discarded          (dt+B+C)
//   MODE 2: fp32 single output F0                              (out_proj)
// ---------------------------------------------------------------------------
template<int BM, int BN, int MODE>
__global__ __launch_bounds__(512) void gemm_mfma(
    const unsigned short* __restrict__ A,   // [M][K] bf16
    const unsigned short* __restrict__ Bt,  // [N][K] bf16
    const float* __restrict__ b0, const float* __restrict__ b1,
    const float* __restrict__ b2,
    float* __restrict__ F0, float* __restrict__ F1, float* __restrict__ F2,
    unsigned short* __restrict__ U0, unsigned short* __restrict__ U1,
    int M, int N, int K, int NS)
{
    constexpr int MF  = BM / 32;   // m-frags per wave (wave covers BM/2 rows)
    constexpr int NF  = BN / 64;   // n-frags per wave (wave covers BN/4 cols)
    constexpr int ACW = BM / 64;   // A 8-row chunks staged per wave (8 waves)
    constexpr int BCW = BN / 64;   // B 8-row chunks staged per wave

    __shared__ unsigned short Asl[2][BM * 64];
    __shared__ unsigned short Bsl[2][BN * 64];

    const int tid  = threadIdx.x;
    const int wave = tid >> 6;     // 0..7
    const int lane = tid & 63;

    // XCD-aware bijective swizzle (all call sites have nwg % 8 == 0).
    const int gx  = gridDim.x, gy = gridDim.y;
    const int bid = blockIdx.y * gx + blockIdx.x;
    const int q   = (gx * gy) >> 3;
    const int nb  = (bid & 7) * q + (bid >> 3);
    const int by  = nb % gy;
    const int bx  = nb / gy;

    const int row0 = by * BM;
    const int col0 = bx * BN;
    const int wr   = (wave >> 2) * (BM / 2);   // wave-row
    const int wc   = (wave & 3) * (BN / 4);    // wave-col

    const int srow = lane >> 3;                          // row within 8-row chunk
    const int scol = ((lane & 7) ^ (lane >> 3)) * 8;     // pre-swizzled source col

    auto stage = [&](int buf, int kt) {
        #pragma unroll
        for (int i = 0; i < ACW; ++i) {
            const int ch = wave * ACW + i;
            gload_lds16(A + (size_t)(row0 + ch * 8 + srow) * K + kt + scol,
                        &Asl[buf][ch * 512]);
        }
        #pragma unroll
        for (int i = 0; i < BCW; ++i) {
            const int ch = wave * BCW + i;
            gload_lds16(Bt + (size_t)(col0 + ch * 8 + srow) * K + kt + scol,
                        &Bsl[buf][ch * 512]);
        }
    };

    f32x4 acc[MF][NF];
    #pragma unroll
    for (int m = 0; m < MF; ++m)
        #pragma unroll
        for (int n = 0; n < NF; ++n)
            acc[m][n] = (f32x4){0.f, 0.f, 0.f, 0.f};

    stage(0, 0);
    __syncthreads();

    const int nk = K >> 6;
    int cur = 0;
    for (int kt = 0; kt < nk; ++kt) {
        if (kt + 1 < nk) stage(cur ^ 1, (kt + 1) << 6);

        short8 af[MF][2], bf[NF][2];
        const int lrow  = lane & 15;
        const int xsw   = (lane & 7) * 8;                // read-side XOR
        const int cbase = (lane >> 4) * 8;
        #pragma unroll
        for (int m = 0; m < MF; ++m)
            #pragma unroll
            for (int kk = 0; kk < 2; ++kk)
                af[m][kk] = *(const short8*)
                    &Asl[cur][(wr + m * 16 + lrow) * 64 + ((kk * 32 + cbase) ^ xsw)];
        #pragma unroll
        for (int n = 0; n < NF; ++n)
            #pragma unroll
            for (int kk = 0; kk < 2; ++kk)
                bf[n][kk] = *(const short8*)
                    &Bsl[cur][(wc + n * 16 + lrow) * 64 + ((kk * 32 + cbase) ^ xsw)];

        #pragma unroll
        for (int m = 0; m < MF; ++m)
            #pragma unroll
            for (int n = 0; n < NF; ++n) {
                acc[m][n] = __builtin_amdgcn_mfma_f32_16x16x32_bf16(
                    af[m][0], bf[n][0], acc[m][n], 0, 0, 0);
                acc[m][n] = __builtin_amdgcn_mfma_f32_16x16x32_bf16(
                    af[m][1], bf[n][1], acc[m][n], 0, 0, 0);
            }
        __syncthreads();   // drains prefetch vmcnt + protects cur from overwrite
        cur ^= 1;
    }

    // epilogue: C/D layout col=lane&15, row=(lane>>4)*4+j
    const int crow = (lane >> 4) * 4;
    const int ccol = lane & 15;
    #pragma unroll
    for (int m = 0; m < MF; ++m)
        #pragma unroll
        for (int n = 0; n < NF; ++n) {
            const int c = col0 + wc + n * 16 + ccol;
            if (MODE == 0) {
                const float bv = b0[c];
                unsigned short* dst = (c < NS) ? (U0 + c) : (U1 + (c - NS));
                #pragma unroll
                for (int j = 0; j < 4; ++j) {
                    const int r = row0 + wr + m * 16 + crow + j;
                    dst[(size_t)r * NS] = f2b(acc[m][n][j] + bv);
                }
            } else if (MODE == 1) {
                if (c < 2048) {
                    const float bv = b0[c];
                    #pragma unroll
                    for (int j = 0; j < 4; ++j) {
                        const int r = row0 + wr + m * 16 + crow + j;
                        float v = acc[m][n][j] + bv;
                        v = (v > 20.0f) ? v : log1pf(__expf(v));
                        U0[(size_t)r * 2048 + c] = f2b(v);
                    }
                } else if (c < 2064) {
                    const float bv = b1[c - 2048];
                    #pragma unroll
                    for (int j = 0; j < 4; ++j) {
                        const int r = row0 + wr + m * 16 + crow + j;
                        F1[(size_t)r * 16 + (c - 2048)] = acc[m][n][j] + bv;
                    }
                } else if (c < 2080) {
                    const float bv = b2[c - 2064];
                    #pragma unroll
                    for (int j = 0; j < 4; ++j) {
                        const int r = row0 + wr + m * 16 + crow + j;
                        F2[(size_t)r * 16 + (c - 2064)] = acc[m][n][j] + bv;
                    }
                }   // pad columns: discard
            } else {
                const float bv = b0[c];
                #pragma unroll
                for (int j = 0; j < 4; ++j) {
                    const int r = row0 + wr + m * 16 + crow + j;
                    F0[(size_t)r * NS + c] = acc[m][n][j] + bv;
                }
            }
        }
}

// ---------------------------------------------------------------------------
// Depthwise conv (window 4, SAME: taps t-1..t+2) + bias + SiLU.
// Vectorized: 8 channels per thread, short8 loads/stores (G13).
// ---------------------------------------------------------------------------
__global__ __launch_bounds__(256) void conv_silu(
    const unsigned short* __restrict__ xzb, const float* __restrict__ cw,
    const float* __restrict__ cb, unsigned short* __restrict__ xcb)
{
    const int idx = blockIdx.x * 256 + threadIdx.x;   // over M*DI/8
    const int nd8 = DI_ / 8;
    const int d0  = (idx & (nd8 - 1)) * 8;
    const int r   = idx / nd8;                         // 0..M-1
    const int t   = r & (L_ - 1);
    const int b   = r >> 10;

    float acc[8];
    #pragma unroll
    for (int j = 0; j < 8; ++j) acc[j] = cb[d0 + j];

    #pragma unroll
    for (int w = 0; w < 4; ++w) {
        const int tt = t + w - 1;
        if (tt >= 0 && tt < L_) {
            const short8 v = *(const short8*)(xzb + ((size_t)(b * L_ + tt)) * DI_ + d0);
            #pragma unroll
            for (int j = 0; j < 8; ++j)
                acc[j] = fmaf(b2f((unsigned short)v[j]), cw[w * DI_ + d0 + j], acc[j]);
        }
    }
    short8 o;
    #pragma unroll
    for (int j = 0; j < 8; ++j) {
        const float s = acc[j] / (1.0f + __expf(-acc[j]));
        o[j] = (short)f2b(s);
    }
    *(short8*)(xcb + (size_t)r * DI_ + d0) = o;
}

// ---------------------------------------------------------------------------
// Chunked selective scan, one CHANNEL per lane, 16 states in registers.
// NCH=64 chunks of TL=16 (16 waves/CU for p1/p2); Pc/Hc stored bf16.
// ---------------------------------------------------------------------------
#define NCH_ 64
#define TL_  (L_ / NCH_)   // 16

__global__ __launch_bounds__(256) void scan_part1(
    const unsigned short* __restrict__ dt, const unsigned short* __restrict__ xcb,
    const float* __restrict__ Bm, const float* __restrict__ A,
    unsigned short* __restrict__ Pc, unsigned short* __restrict__ Hc)
{
    const int tid = threadIdx.x;
    const int d   = blockIdx.x * 256 + tid;
    const int b   = blockIdx.y;
    const int j   = blockIdx.z;
    const int t0  = j * TL_;

    __shared__ float s_Bm[TL_ * DS_];                  // 256 floats
    {
        const float* src = Bm + ((size_t)b * L_ + t0) * DS_;
        s_Bm[tid] = src[tid];
    }
    float a[DS_];
    #pragma unroll
    for (int qq = 0; qq < 4; ++qq)
        *(float4*)&a[qq * 4] = *(const float4*)(A + (size_t)d * DS_ + qq * 4);
    __syncthreads();

    const unsigned short* dtp = dt + ((size_t)b * L_ + t0) * DI_ + d;
    const unsigned short* xcp = xcb + ((size_t)b * L_ + t0) * DI_ + d;

    float h[DS_] = {};
    float P[DS_];
    #pragma unroll
    for (int s = 0; s < DS_; ++s) P[s] = 1.0f;

    float dtv = b2f(dtp[0]), xcv = b2f(xcp[0]);
    #pragma unroll 4
    for (int t = 0; t < TL_; ++t) {
        float dtv_n = 0.f, xcv_n = 0.f;
        if (t + 1 < TL_) {
            dtv_n = b2f(dtp[(size_t)(t + 1) * DI_]);
            xcv_n = b2f(xcp[(size_t)(t + 1) * DI_]);
        }
        const float dx = dtv * xcv;
        #pragma unroll
        for (int qq = 0; qq < 4; ++qq) {
            const float4 bm = *(const float4*)&s_Bm[t * DS_ + qq * 4];
            #pragma unroll
            for (int i = 0; i < 4; ++i) {
                const int s = qq * 4 + i;
                const float bv = (i == 0) ? bm.x : (i == 1) ? bm.y : (i == 2) ? bm.z : bm.w;
                const float dA = __expf(dtv * a[s]);
                P[s] *= dA;
                h[s] = fmaf(dA, h[s], dx * bv);
            }
        }
        dtv = dtv_n; xcv = xcv_n;
    }
    const size_t o0 = (((size_t)b * NCH_ + j) * DS_) * DI_ + d;
    #pragma unroll
    for (int s = 0; s < DS_; ++s) {
        Pc[o0 + (size_t)s * DI_] = f2b(P[s]);
        Hc[o0 + (size_t)s * DI_] = f2b(h[s]);
    }
}

__global__ __launch_bounds__(256) void scan_combine(
    const unsigned short* __restrict__ Pc, unsigned short* __restrict__ Hc)
{
    const size_t idx = (size_t)blockIdx.x * 256 + threadIdx.x;   // over BN*DS*DI
    const size_t b   = idx / (DS_ * DI_);
    const size_t rem = idx % (DS_ * DI_);
    const size_t base   = b * ((size_t)NCH_ * DS_ * DI_) + rem;
    const size_t stride = (size_t)DS_ * DI_;
    float h = 0.f;
    #pragma unroll 8
    for (int j = 0; j < NCH_; ++j) {
        const size_t o = base + (size_t)j * stride;
        const float P  = b2f(Pc[o]);
        const float hl = b2f(Hc[o]);
        Hc[o] = f2b(h);            // incoming state for chunk j
        h = fmaf(P, h, hl);
    }
}

__global__ __launch_bounds__(256) void scan_part2(
    const unsigned short* __restrict__ dt, const unsigned short* __restrict__ xcb,
    const unsigned short* __restrict__ gate,     // bf16
    const float* __restrict__ Bm, const float* __restrict__ Cm,
    const float* __restrict__ A, const float* __restrict__ Dp,
    const unsigned short* __restrict__ Hin, unsigned short* __restrict__ ygb)
{
    const int tid = threadIdx.x;
    const int d   = blockIdx.x * 256 + tid;
    const int b   = blockIdx.y;
    const int j   = blockIdx.z;
    const int t0  = j * TL_;

    __shared__ float s_Bm[TL_ * DS_];
    __shared__ float s_Cm[TL_ * DS_];
    {
        const float* bsrc = Bm + ((size_t)b * L_ + t0) * DS_;
        const float* csrc = Cm + ((size_t)b * L_ + t0) * DS_;
        s_Bm[tid] = bsrc[tid];
        s_Cm[tid] = csrc[tid];
    }
    float a[DS_];
    #pragma unroll
    for (int qq = 0; qq < 4; ++qq)
        *(float4*)&a[qq * 4] = *(const float4*)(A + (size_t)d * DS_ + qq * 4);
    const float dp = Dp[d];

    float h[DS_];
    {
        const size_t o0 = (((size_t)b * NCH_ + j) * DS_) * DI_ + d;
        #pragma unroll
        for (int s = 0; s < DS_; ++s) h[s] = b2f(Hin[o0 + (size_t)s * DI_]);
    }
    __syncthreads();

    const size_t rbase = ((size_t)b * L_ + t0) * DI_ + d;
    const unsigned short* dtp = dt   + rbase;
    const unsigned short* xcp = xcb  + rbase;
    const unsigned short* gvp = gate + rbase;
    unsigned short* yp = ygb + rbase;

    float dtv = b2f(dtp[0]), xcv = b2f(xcp[0]), gv = b2f(gvp[0]);
    #pragma unroll 4
    for (int t = 0; t < TL_; ++t) {
        float dtv_n = 0.f, xcv_n = 0.f, gv_n = 0.f;
        if (t + 1 < TL_) {
            dtv_n = b2f(dtp[(size_t)(t + 1) * DI_]);
            xcv_n = b2f(xcp[(size_t)(t + 1) * DI_]);
            gv_n  = b2f(gvp[(size_t)(t + 1) * DI_]);
        }
        const float dx = dtv * xcv;
        float y0 = 0.f, y1 = 0.f, y2 = 0.f, y3 = 0.f;
        #pragma unroll
        for (int qq = 0; qq < 4; ++qq) {
            const float4 bm = *(const float4*)&s_Bm[t * DS_ + qq * 4];
            const float4 cm = *(const float4*)&s_Cm[t * DS_ + qq * 4];
            #pragma unroll
            for (int i = 0; i < 4; ++i) {
                const int s = qq * 4 + i;
                const float bv = (i == 0) ? bm.x : (i == 1) ? bm.y : (i == 2) ? bm.z : bm.w;
                const float cv = (i == 0) ? cm.x : (i == 1) ? cm.y : (i == 2) ? cm.z : cm.w;
                const float dA = __expf(dtv * a[s]);
                h[s] = fmaf(dA, h[s], dx * bv);
                if (i == 0) y0 = fmaf(h[s], cv, y0);
                else if (i == 1) y1 = fmaf(h[s], cv, y1);
                else if (i == 2) y2 = fmaf(h[s], cv, y2);
                else y3 = fmaf(h[s], cv, y3);
            }
        }
        float y = (y0 + y1) + (y2 + y3);
        y = fmaf(xcv, dp, y);
        const float r = y * (gv / (1.0f + __expf(-gv)));
        yp[(size_t)t * DI_] = f2b(r);
        dtv = dtv_n; xcv = xcv_n; gv = gv_n;
    }
}

// ---------------------------------------------------------------------------
extern "C" void kernel_launch(void* const* d_in, const int* in_sizes, int n_in,
                              void* d_out, int out_size, void* d_ws, size_t ws_size,
                              hipStream_t stream)
{
    const float* x      = (const float*)d_in[0];
    const float* in_w   = (const float*)d_in[1];
    const float* in_b   = (const float*)d_in[2];
    const float* conv_w = (const float*)d_in[3];
    const float* conv_b = (const float*)d_in[4];
    const float* A      = (const float*)d_in[5];
    const float* Dp     = (const float*)d_in[6];
    const float* B_w    = (const float*)d_in[7];
    const float* B_b    = (const float*)d_in[8];
    const float* C_w    = (const float*)d_in[9];
    const float* C_b    = (const float*)d_in[10];
    const float* dt_w   = (const float*)d_in[11];
    const float* dt_b   = (const float*)d_in[12];
    const float* out_w  = (const float*)d_in[13];
    const float* out_b  = (const float*)d_in[14];
    float* out = (float*)d_out;

    // ---- workspace layout (aliased) ----
    unsigned short* dtb = (unsigned short*)d_ws;   // [M][DI] bf16, 8MB
    float* Bm   = (float*)(dtb + (size_t)M_ * DI_);          // [M][16] 128KB
    float* Cm   = Bm  + (size_t)M_ * DS_;                    // [M][16] 128KB
    unsigned short* w3  = (unsigned short*)(Cm + (size_t)M_ * DS_); // out_w^T  4MB
    unsigned short* w1  = w3  + (size_t)DM_ * DI_;                  // in_w^T   8MB
    unsigned short* xb  = w1  + (size_t)2 * DI_ * DM_;              // x bf16   4MB
    unsigned short* w2  = xb  + (size_t)M_ * DM_;                   // dtBC^T   8.5MB
    unsigned short* xcb = w2  + (size_t)NBC_ * DI_;                 // xc bf16  8MB
    unsigned short* xzb = xcb + (size_t)M_ * DI_;                   // xz bf16  8MB
    unsigned short* gtb = xzb + (size_t)M_ * DI_;                   // gate bf16 8MB
    unsigned short* ygb = xcb;                     // alias: p2 reads/writes same offsets
    unsigned short* Pc = w1;                       // bf16 8MB over w1 (dead after in_proj)
    unsigned short* Hc = xb;                       // bf16 8MB over xb + w2 head (dead after dtBC GEMM)

    // 1) fused prep: xb, w1, w2 (incl. bc rows), w3 in ONE dispatch
    prep<<<12544, 256, 0, stream>>>(x, in_w, dt_w, out_w, B_w, C_w, xb, w1, w2, w3);

    // 2) [xzb | gtb] = bf16(x @ in_w + in_b)   (M=2048, N=4096, K=1024)
    gemm_mfma<64, 128, 0><<<dim3(2 * DI_ / 128, M_ / 64), 512, 0, stream>>>(
        xb, w1, in_b, nullptr, nullptr,
        nullptr, nullptr, nullptr, xzb, gtb, M_, 2 * DI_, DM_, DI_);

    // 3) depthwise conv + silu (bf16 xcb), vectorized x8
    conv_silu<<<(BN_ * L_ * DI_ / 8) / 256, 256, 0, stream>>>(xzb, conv_w, conv_b, xcb);

    // 4) dtb(bf16) = softplus(xc @ dt_w + dt_b); Bm,Cm fp32
    gemm_mfma<64, 128, 1><<<dim3(NBC_ / 128, M_ / 64), 512, 0, stream>>>(
        xcb, w2, dt_b, B_b, C_b,
        nullptr, Bm, Cm, dtb, nullptr, M_, NBC_, DI_, NBC_);

    // 5) chunked scan: part1 -> combine -> part2 (writes bf16 ygb)
    scan_part1<<<dim3(DI_ / 256, BN_, NCH_), 256, 0, stream>>>(
        dtb, xcb, Bm, A, Pc, Hc);
    scan_combine<<<(BN_ * DI_ * DS_) / 256, 256, 0, stream>>>(Pc, Hc);
    scan_part2<<<dim3(DI_ / 256, BN_, NCH_), 256, 0, stream>>>(
        dtb, xcb, gtb, Bm, Cm, A, Dp, Hc, ygb);

    // 6) out = yg @ out_w + out_b   (M=2048, N=1024, K=2048)
    gemm_mfma<64, 64, 2><<<dim3(DM_ / 64, M_ / 64), 512, 0, stream>>>(
        ygb, w3, out_b, nullptr, nullptr,
        out, nullptr, nullptr, nullptr, nullptr, M_, DM_, DI_, DM_);
}